// Round 8
// baseline (265.716 us; speedup 1.0000x reference)
//
#include <hip/hip_runtime.h>

typedef _Float16 f16;
typedef _Float16 f16x8 __attribute__((ext_vector_type(8)));
typedef _Float16 f16x4 __attribute__((ext_vector_type(4)));
typedef float f32x4 __attribute__((ext_vector_type(4)));

#define MFMA16(a, b, c) __builtin_amdgcn_mfma_f32_16x16x32_f16(a, b, c, 0, 0, 0)

// LDS-only barrier: drains LDS ops but leaves global loads/stores in flight.
// Legal: every barrier here protects only LDS data (weights read-only, out write-only).
__device__ __forceinline__ void barrier_lds() {
    asm volatile("s_waitcnt lgkmcnt(0)" ::: "memory");
    __builtin_amdgcn_s_barrier();
}

// ---------------- weight packing (A-operand layout) ----------------
__device__ __forceinline__ void pack_one(int local, const float* __restrict__ src,
                                         f16* __restrict__ dst, int K, int R, int transpose) {
    int i = local & 7;
    int l = (local >> 3) & 63;
    int p = local >> 9;
    int rt16 = R >> 4;
    int rb = p % rt16;
    int kb = p / rt16;
    int k = kb * 32 + ((l >> 4) << 3) + i;
    int r = rb * 16 + (l & 15);
    float v = transpose ? src[k * R + r] : src[r * K + k];
    dst[local] = (f16)v;
}

__global__ void pack_weights(const float* __restrict__ w00, const float* __restrict__ w01,
                             const float* __restrict__ w10, const float* __restrict__ w110,
                             const float* __restrict__ w111, const float* __restrict__ W0e,
                             const float* __restrict__ W1o, const float* __restrict__ W1e,
                             f16* __restrict__ dst) {
    int idx = blockIdx.x * 256 + threadIdx.x;
    if (idx < 65536)        pack_one(idx,          w00,  dst,          256, 256, 0);
    else if (idx < 98304)   pack_one(idx - 65536,  w01,  dst + 65536,  128, 256, 0);
    else if (idx < 131072)  pack_one(idx - 98304,  w10,  dst + 98304,  256, 128, 0);
    else if (idx < 147456)  pack_one(idx - 131072, w110, dst + 131072, 128, 128, 0);
    else if (idx < 163840)  pack_one(idx - 147456, w111, dst + 147456, 128, 128, 0);
    else if (idx < 262144)  pack_one(idx - 163840, W0e,  dst + 163840, 384, 256, 1);
    else if (idx < 311296)  pack_one(idx - 262144, W1o,  dst + 262144, 384, 128, 1);
    else                    pack_one(idx - 311296, W1e,  dst + 311296, 128, 128, 1);
}

// ---------------- main fused kernel ----------------
// r5 phase structure + rolled 1-deep-prefetch loops, r6 48KiB memory map:
//   STA (16K): S -> (after P1/P4 read it) T[:,0:256] -> M0,M1
//   V   (24K): V_j planes -> p5_j in place
//   T2B (8K) : T[:,256:384] (p4/p3) -> M2
// s and A3 live in registers. 48K x 3 = 144K -> 3 blocks/CU (VGPR <= 85).
#define NT 32
#define STA    0                        // [32][256] f16, pitch 512B (16 KiB)
#define VB(j)  (16384 + (j) * 8192)     // [32][128] f16, pitch 256B (3 x 8 KiB)
#define T2B    40960                    // [32][128] f16, pitch 256B (8 KiB)
#define MB(j)  ((j) == 2 ? T2B : (STA + (j) * 8192))
#define LDS_BYTES 49152

__device__ __forceinline__ f16x8 afrag(const unsigned char* lds, int base, int pitchh,
                                       int row0, int k0, int lr, int lg) {
    int row = row0 + lr;
    int off = base + row * (pitchh * 2) + (((k0 + (lg << 3)) * 2) ^ ((row & 7) << 4));
    return *(const f16x8*)(lds + off);
}
__device__ __forceinline__ f16x4 ldsv4(const unsigned char* lds, int base, int pitchh,
                                       int row, int col) {
    int off = base + row * (pitchh * 2) + ((col * 2) ^ ((row & 7) << 4));
    return *(const f16x4*)(lds + off);
}
__device__ __forceinline__ void stsv4(unsigned char* lds, int base, int pitchh,
                                      int row, int col, f16x4 v) {
    int off = base + row * (pitchh * 2) + ((col * 2) ^ ((row & 7) << 4));
    *(f16x4*)(lds + off) = v;
}
__device__ __forceinline__ void ldss(unsigned char* lds, int base, int pitchh,
                                     int row, int col, float v) {
    int off = base + row * (pitchh * 2) + ((col * 2) ^ ((row & 7) << 4));
    *(f16*)(lds + off) = (f16)v;
}
__device__ __forceinline__ f16x8 wfrag(const f16* __restrict__ panel, int rt16, int kb,
                                       int rb, int lane) {
    return *(const f16x8*)(panel + (size_t)((kb * rt16 + rb) * 512 + lane * 8));
}

__global__ __launch_bounds__(512, 6)
void node_tp(const float* __restrict__ nf, const f16* __restrict__ wp,
             float* __restrict__ out, int n_nodes) {
    __shared__ __align__(16) unsigned char lds[LDS_BYTES];
    const int tid = threadIdx.x;
    const int lane = tid & 63;
    const int wv = tid >> 6;
    const int z0 = blockIdx.x * NT;
    const int nvalid = min(NT, n_nodes - z0);
    const int lr = lane & 15;
    const int lg = lane >> 4;
    const int ng = wv >> 2;   // node-tile (of 2) for split phases
    const int wr = wv & 3;    // channel-tile pair for split phases (128-wide)

    const f16* w00p  = wp;
    const f16* w01p  = wp + 65536;
    const f16* w10p  = wp + 98304;
    const f16* w110p = wp + 131072;
    const f16* w111p = wp + 147456;
    const f16* W0ep  = wp + 163840;
    const f16* W1op  = wp + 262144;
    const f16* W1ep  = wp + 311296;

    const float C000 = 0.0625f;               // 1/sqrt(256)
    const float C011 = 0.08838834764831843f;  // 1/sqrt(128)
    const float C101 = 0.0625f;
    const float C110 = 0.05103103630798287f;  // 1/sqrt(384)
    const float C111 = 0.0625f;               // 1/16
    const float RS384 = 0.05103103630798287f;
    const float RS128 = 0.08838834764831843f;

    // ---- P0: stage node_feat -> LDS (swizzled, [node][channel]) ----
    #pragma unroll 5
    for (int q = tid; q < NT * 160; q += 512) {
        int row = q / 160;
        int c4 = q - row * 160;
        float4 v4 = make_float4(0.f, 0.f, 0.f, 0.f);
        if (row < nvalid)
            v4 = ((const float4*)(nf + (size_t)(z0 + row) * 640))[c4];
        int c = c4 * 4;
        if (c < 256) {
            f16x4 h = {(f16)v4.x, (f16)v4.y, (f16)v4.z, (f16)v4.w};
            int off = STA + row * 512 + ((c * 2) ^ ((row & 7) << 4));
            *(f16x4*)(lds + off) = h;
        } else {
            float vv[4] = {v4.x, v4.y, v4.z, v4.w};
            #pragma unroll
            for (int e = 0; e < 4; ++e) {
                int m = c - 256 + e;
                int u = m / 3;
                int j = m - u * 3;
                ldss(lds, VB(j), 128, row, u, vv[e]);
            }
        }
    }
    // s for p1/p2 epilogues in registers (r6-proven geometry)
    f16x4 s4r[2][2];
    #pragma unroll
    for (int rt = 0; rt < 2; ++rt)
        #pragma unroll
        for (int nt = 0; nt < 2; ++nt) {
            int node = nt * 16 + lr;
            float4 f = make_float4(0.f, 0.f, 0.f, 0.f);
            if (node < nvalid)
                f = *(const float4*)(nf + (size_t)(z0 + node) * 640 + wv * 32 + rt * 16 + lg * 4);
            s4r[rt][nt] = f16x4{(f16)f.x, (f16)f.y, (f16)f.z, (f16)f.w};
        }
    barrier_lds();

    // ---- P1: A1^T = w00 @ S^T (rolled, 1-deep prefetch) -> acc1 regs ----
    f32x4 acc1[2][2] = {};
    {
        f16x8 a0 = wfrag(w00p, 16, 0, 2 * wv, lane);
        f16x8 a1 = wfrag(w00p, 16, 0, 2 * wv + 1, lane);
        #pragma unroll 1
        for (int ks = 0; ks < 8; ++ks) {
            int kn = ks + 1 < 8 ? ks + 1 : ks;
            f16x8 n0 = wfrag(w00p, 16, kn, 2 * wv, lane);
            f16x8 n1 = wfrag(w00p, 16, kn, 2 * wv + 1, lane);
            #pragma unroll
            for (int nt = 0; nt < 2; ++nt) {
                f16x8 b = afrag(lds, STA, 256, nt * 16, ks * 32, lr, lg);
                acc1[0][nt] = MFMA16(a0, b, acc1[0][nt]);
                acc1[1][nt] = MFMA16(a1, b, acc1[1][nt]);
            }
            a0 = n0; a1 = n1;
        }
    }
    // ---- P4: A3^T = w10 @ S^T (rolled) -> acc3 regs ----
    f32x4 acc3[2] = {};
    {
        f16x8 a0 = wfrag(w10p, 8, 0, 2 * wr, lane);
        f16x8 a1 = wfrag(w10p, 8, 0, 2 * wr + 1, lane);
        #pragma unroll 1
        for (int ks = 0; ks < 8; ++ks) {
            int kn = ks + 1 < 8 ? ks + 1 : ks;
            f16x8 n0 = wfrag(w10p, 8, kn, 2 * wr, lane);
            f16x8 n1 = wfrag(w10p, 8, kn, 2 * wr + 1, lane);
            f16x8 b = afrag(lds, STA, 256, ng * 16, ks * 32, lr, lg);
            acc3[0] = MFMA16(a0, b, acc3[0]);
            acc3[1] = MFMA16(a1, b, acc3[1]);
            a0 = n0; a1 = n1;
        }
    }
    // ---- P2: A4j^T = w110 @ Vj^T ; p4 -> T2B (fresh buffer) ----
    {
        f32x4 a4[3][2] = {};  // [j][r2]
        #pragma unroll
        for (int ks = 0; ks < 4; ++ks) {
            f16x8 a0 = wfrag(w110p, 8, ks, 2 * wr, lane);
            f16x8 a1 = wfrag(w110p, 8, ks, 2 * wr + 1, lane);
            #pragma unroll
            for (int j = 0; j < 3; ++j) {
                f16x8 b = afrag(lds, VB(j), 128, ng * 16, ks * 32, lr, lg);
                a4[j][0] = MFMA16(a0, b, a4[j][0]);
                a4[j][1] = MFMA16(a1, b, a4[j][1]);
            }
        }
        #pragma unroll
        for (int r2 = 0; r2 < 2; ++r2) {
            int node = ng * 16 + lr;
            int u0 = (2 * wr + r2) * 16 + lg * 4;
            float p4[4] = {0.f, 0.f, 0.f, 0.f};
            #pragma unroll
            for (int j = 0; j < 3; ++j) {
                f16x4 v4 = ldsv4(lds, VB(j), 128, node, u0);
                #pragma unroll
                for (int r = 0; r < 4; ++r)
                    p4[r] += (float)v4[r] * a4[j][r2][r];
            }
            f16x4 t4;
            #pragma unroll
            for (int r = 0; r < 4; ++r) t4[r] = (f16)(C110 * p4[r]);
            stsv4(lds, T2B, 128, node, u0, t4);
        }
    }
    barrier_lds();  // all S reads done -> STA writable

    // p1 = C000 * s(regs) * A1 -> STA in place (becomes T[:,0:256])
    #pragma unroll
    for (int rt = 0; rt < 2; ++rt)
        #pragma unroll
        for (int nt = 0; nt < 2; ++nt) {
            f16x4 t4;
            #pragma unroll
            for (int r = 0; r < 4; ++r)
                t4[r] = (f16)(C000 * (float)s4r[rt][nt][r] * acc1[rt][nt][r]);
            stsv4(lds, STA, 256, nt * 16 + lr, wv * 32 + rt * 16 + lg * 4, t4);
        }
    barrier_lds();  // T = [STA|T2B] ready

    // ---- P3: out_0e^T = W0e^T @ T^T / sqrt(384) (rolled, region-switch) ----
    {
        f32x4 acc[2][2] = {};
        f16x8 a0 = wfrag(W0ep, 16, 0, 2 * wv, lane);
        f16x8 a1 = wfrag(W0ep, 16, 0, 2 * wv + 1, lane);
        #pragma unroll 1
        for (int ks = 0; ks < 12; ++ks) {
            int kn = ks + 1 < 12 ? ks + 1 : ks;
            f16x8 n0 = wfrag(W0ep, 16, kn, 2 * wv, lane);
            f16x8 n1 = wfrag(W0ep, 16, kn, 2 * wv + 1, lane);
            #pragma unroll
            for (int nt = 0; nt < 2; ++nt) {
                f16x8 b = (ks < 8) ? afrag(lds, STA, 256, nt * 16, ks * 32, lr, lg)
                                   : afrag(lds, T2B, 128, nt * 16, (ks - 8) * 32, lr, lg);
                acc[0][nt] = MFMA16(a0, b, acc[0][nt]);
                acc[1][nt] = MFMA16(a1, b, acc[1][nt]);
            }
            a0 = n0; a1 = n1;
        }
        #pragma unroll
        for (int rt = 0; rt < 2; ++rt)
            #pragma unroll
            for (int nt = 0; nt < 2; ++nt) {
                int node = nt * 16 + lr;
                if (node < nvalid) {
                    int o = wv * 32 + rt * 16 + lg * 4;
                    float4 o4;
                    o4.x = RS384 * acc[rt][nt][0];
                    o4.y = RS384 * acc[rt][nt][1];
                    o4.z = RS384 * acc[rt][nt][2];
                    o4.w = RS384 * acc[rt][nt][3];
                    *(float4*)(&out[(size_t)(z0 + node) * 1024 + o]) = o4;
                }
            }
    }

    // ---- P5 (j-loop): A2j -> p2 (STA); p3 from acc3 regs (T2B); out1o += W1o^T @ T^T ----
    f32x4 acc1o[2][3] = {};  // [r2][j]
    #pragma unroll
    for (int j = 0; j < 3; ++j) {
        f32x4 a2[2][2] = {};
        #pragma unroll
        for (int ks = 0; ks < 4; ++ks) {
            f16x8 a0 = wfrag(w01p, 16, ks, 2 * wv, lane);
            f16x8 a1 = wfrag(w01p, 16, ks, 2 * wv + 1, lane);
            #pragma unroll
            for (int nt = 0; nt < 2; ++nt) {
                f16x8 b = afrag(lds, VB(j), 128, nt * 16, ks * 32, lr, lg);
                a2[0][nt] = MFMA16(a0, b, a2[0][nt]);
                a2[1][nt] = MFMA16(a1, b, a2[1][nt]);
            }
        }
        barrier_lds();  // previous T readers (P3 or W1o_{j-1}) done
        #pragma unroll
        for (int rt = 0; rt < 2; ++rt)
            #pragma unroll
            for (int nt = 0; nt < 2; ++nt) {
                f16x4 t4;
                #pragma unroll
                for (int r = 0; r < 4; ++r)
                    t4[r] = (f16)(C011 * (float)s4r[rt][nt][r] * a2[rt][nt][r]);
                stsv4(lds, STA, 256, nt * 16 + lr, wv * 32 + rt * 16 + lg * 4, t4);
            }
        #pragma unroll
        for (int r2 = 0; r2 < 2; ++r2) {
            f16x4 v4 = ldsv4(lds, VB(j), 128, ng * 16 + lr, (2 * wr + r2) * 16 + lg * 4);
            f16x4 t4;
            #pragma unroll
            for (int r = 0; r < 4; ++r)
                t4[r] = (f16)(C101 * (float)v4[r] * acc3[r2][r]);
            stsv4(lds, T2B, 128, ng * 16 + lr, (2 * wr + r2) * 16 + lg * 4, t4);
        }
        barrier_lds();  // [p2|p3] ready
        {
            f16x8 a0 = wfrag(W1op, 8, 0, 2 * wr, lane);
            f16x8 a1 = wfrag(W1op, 8, 0, 2 * wr + 1, lane);
            #pragma unroll 1
            for (int ks = 0; ks < 12; ++ks) {
                int kn = ks + 1 < 12 ? ks + 1 : ks;
                f16x8 n0 = wfrag(W1op, 8, kn, 2 * wr, lane);
                f16x8 n1 = wfrag(W1op, 8, kn, 2 * wr + 1, lane);
                f16x8 b = (ks < 8) ? afrag(lds, STA, 256, ng * 16, ks * 32, lr, lg)
                                   : afrag(lds, T2B, 128, ng * 16, (ks - 8) * 32, lr, lg);
                acc1o[0][j] = MFMA16(a0, b, acc1o[0][j]);
                acc1o[1][j] = MFMA16(a1, b, acc1o[1][j]);
                a0 = n0; a1 = n1;
            }
        }
    }
    barrier_lds();  // last W1o reads done -> STA/T2B writable for M

    // out_1o store (registers only)
    #pragma unroll
    for (int r2 = 0; r2 < 2; ++r2) {
        int node = ng * 16 + lr;
        if (node < nvalid) {
            int o0 = (2 * wr + r2) * 16 + lg * 4;
            float vals[12];
            #pragma unroll
            for (int r = 0; r < 4; ++r)
                #pragma unroll
                for (int j = 0; j < 3; ++j)
                    vals[r * 3 + j] = RS384 * acc1o[r2][j][r];
            size_t base = (size_t)(z0 + node) * 1024 + 256 + 3 * o0;
            #pragma unroll
            for (int qq = 0; qq < 3; ++qq) {
                float4 f;
                f.x = vals[qq * 4 + 0]; f.y = vals[qq * 4 + 1];
                f.z = vals[qq * 4 + 2]; f.w = vals[qq * 4 + 3];
                *(float4*)(&out[base + qq * 4]) = f;
            }
        }
    }

    // ---- P6: M_j = w111 @ V_j^T -> M planes (STA, STA+8K, T2B) ----
    #pragma unroll
    for (int j = 0; j < 3; ++j) {
        f32x4 am[2] = {};
        #pragma unroll
        for (int ks = 0; ks < 4; ++ks) {
            f16x8 a0 = wfrag(w111p, 8, ks, 2 * wr, lane);
            f16x8 a1 = wfrag(w111p, 8, ks, 2 * wr + 1, lane);
            f16x8 b = afrag(lds, VB(j), 128, ng * 16, ks * 32, lr, lg);
            am[0] = MFMA16(a0, b, am[0]);
            am[1] = MFMA16(a1, b, am[1]);
        }
        #pragma unroll
        for (int r2 = 0; r2 < 2; ++r2) {
            f16x4 t4;
            #pragma unroll
            for (int r = 0; r < 4; ++r) t4[r] = (f16)am[r2][r];
            stsv4(lds, MB(j), 128, ng * 16 + lr, (2 * wr + r2) * 16 + lg * 4, t4);
        }
    }
    barrier_lds();  // M visible

    // ---- cross: p5_j -> V planes in place ----
    #pragma unroll 1
    for (int q = tid; q < NT * 32; q += 512) {
        int row = q >> 5;
        int col = (q & 31) * 4;
        f16x4 v0 = ldsv4(lds, VB(0), 128, row, col);
        f16x4 v1 = ldsv4(lds, VB(1), 128, row, col);
        f16x4 v2 = ldsv4(lds, VB(2), 128, row, col);
        f16x4 m0 = ldsv4(lds, MB(0), 128, row, col);
        f16x4 m1 = ldsv4(lds, MB(1), 128, row, col);
        f16x4 m2 = ldsv4(lds, MB(2), 128, row, col);
        f16x4 c0, c1, c2;
        #pragma unroll
        for (int r = 0; r < 4; ++r) {
            c0[r] = (f16)(C111 * ((float)v1[r] * (float)m2[r] - (float)v2[r] * (float)m1[r]));
            c1[r] = (f16)(C111 * ((float)v2[r] * (float)m0[r] - (float)v0[r] * (float)m2[r]));
            c2[r] = (f16)(C111 * ((float)v0[r] * (float)m1[r] - (float)v1[r] * (float)m0[r]));
        }
        stsv4(lds, VB(0), 128, row, col, c0);
        stsv4(lds, VB(1), 128, row, col, c1);
        stsv4(lds, VB(2), 128, row, col, c2);
    }
    barrier_lds();  // p5 ready

    // ---- P7: out_1e = W1e^T @ p5^T / sqrt(128) ----
    {
        f32x4 acc[2][3] = {};  // [r2][j]
        #pragma unroll
        for (int j = 0; j < 3; ++j)
            #pragma unroll
            for (int ks = 0; ks < 4; ++ks) {
                f16x8 a0 = wfrag(W1ep, 8, ks, 2 * wr, lane);
                f16x8 a1 = wfrag(W1ep, 8, ks, 2 * wr + 1, lane);
                f16x8 b = afrag(lds, VB(j), 128, ng * 16, ks * 32, lr, lg);
                acc[0][j] = MFMA16(a0, b, acc[0][j]);
                acc[1][j] = MFMA16(a1, b, acc[1][j]);
            }
        #pragma unroll
        for (int r2 = 0; r2 < 2; ++r2) {
            int node = ng * 16 + lr;
            if (node < nvalid) {
                int o0 = (2 * wr + r2) * 16 + lg * 4;
                float vals[12];
                #pragma unroll
                for (int r = 0; r < 4; ++r)
                    #pragma unroll
                    for (int j = 0; j < 3; ++j)
                        vals[r * 3 + j] = RS128 * acc[r2][j][r];
                size_t base = (size_t)(z0 + node) * 1024 + 640 + 3 * o0;
                #pragma unroll
                for (int qq = 0; qq < 3; ++qq) {
                    float4 f;
                    f.x = vals[qq * 4 + 0]; f.y = vals[qq * 4 + 1];
                    f.z = vals[qq * 4 + 2]; f.w = vals[qq * 4 + 3];
                    *(float4*)(&out[base + qq * 4]) = f;
                }
            }
        }
    }
}

extern "C" void kernel_launch(void* const* d_in, const int* in_sizes, int n_in,
                              void* d_out, int out_size, void* d_ws, size_t ws_size,
                              hipStream_t stream) {
    const float* nf   = (const float*)d_in[0];
    const float* w00  = (const float*)d_in[1];
    const float* w01  = (const float*)d_in[2];
    const float* w10  = (const float*)d_in[3];
    const float* w110 = (const float*)d_in[4];
    const float* w111 = (const float*)d_in[5];
    const float* W0e  = (const float*)d_in[6];
    const float* W1o  = (const float*)d_in[7];
    const float* W1e  = (const float*)d_in[8];
    f16* wpack = (f16*)d_ws;  // needs 655,360 bytes

    int n_nodes = in_sizes[0] / 640;
    pack_weights<<<1280, 256, 0, stream>>>(w00, w01, w10, w110, w111, W0e, W1o, W1e, wpack);
    int blocks = (n_nodes + NT - 1) / NT;
    node_tp<<<blocks, 512, 0, stream>>>(nf, wpack, (float*)d_out, n_nodes);
}

// Round 9
// 238.249 us; speedup vs baseline: 1.1153x; 1.1153x over previous
//
#include <hip/hip_runtime.h>

typedef _Float16 f16;
typedef _Float16 f16x8 __attribute__((ext_vector_type(8)));
typedef _Float16 f16x4 __attribute__((ext_vector_type(4)));
typedef float f32x4 __attribute__((ext_vector_type(4)));

#define MFMA16(a, b, c) __builtin_amdgcn_mfma_f32_16x16x32_f16(a, b, c, 0, 0, 0)

// LDS-only barrier: drains LDS ops but leaves global loads/stores in flight.
// Legal: every barrier here protects only LDS data (weights read-only, out write-only).
__device__ __forceinline__ void barrier_lds() {
    asm volatile("s_waitcnt lgkmcnt(0)" ::: "memory");
    __builtin_amdgcn_s_barrier();
}

// ---------------- weight packing (A-operand layout) ----------------
__device__ __forceinline__ void pack_one(int local, const float* __restrict__ src,
                                         f16* __restrict__ dst, int K, int R, int transpose) {
    int i = local & 7;
    int l = (local >> 3) & 63;
    int p = local >> 9;
    int rt16 = R >> 4;
    int rb = p % rt16;
    int kb = p / rt16;
    int k = kb * 32 + ((l >> 4) << 3) + i;
    int r = rb * 16 + (l & 15);
    float v = transpose ? src[k * R + r] : src[r * K + k];
    dst[local] = (f16)v;
}

__global__ void pack_weights(const float* __restrict__ w00, const float* __restrict__ w01,
                             const float* __restrict__ w10, const float* __restrict__ w110,
                             const float* __restrict__ w111, const float* __restrict__ W0e,
                             const float* __restrict__ W1o, const float* __restrict__ W1e,
                             f16* __restrict__ dst) {
    int idx = blockIdx.x * 256 + threadIdx.x;
    if (idx < 65536)        pack_one(idx,          w00,  dst,          256, 256, 0);
    else if (idx < 98304)   pack_one(idx - 65536,  w01,  dst + 65536,  128, 256, 0);
    else if (idx < 131072)  pack_one(idx - 98304,  w10,  dst + 98304,  256, 128, 0);
    else if (idx < 147456)  pack_one(idx - 131072, w110, dst + 131072, 128, 128, 0);
    else if (idx < 163840)  pack_one(idx - 147456, w111, dst + 147456, 128, 128, 0);
    else if (idx < 262144)  pack_one(idx - 163840, W0e,  dst + 163840, 384, 256, 1);
    else if (idx < 311296)  pack_one(idx - 262144, W1o,  dst + 262144, 384, 128, 1);
    else                    pack_one(idx - 311296, W1e,  dst + 311296, 128, 128, 1);
}

// ---------------- main fused kernel ----------------
// 256-thread (4-wave) blocks, NT=32, 48 KiB map -> 3 blocks/CU (LDS-capped),
// only 3 waves/SIMD -> 170 VGPR budget (spill-proof; r8's failure was the
// 8-wave geometry needing <=85). Each wave covers 2x tiles via static h loop.
//   STA (16K): S -> T[:,0:256] -> M0,M1
//   V   (24K): V_j planes -> p5_j in place
//   T2B (8K) : p4/p3 -> M2
#define NT 32
#define STA    0                        // [32][256] f16, pitch 512B (16 KiB)
#define VB(j)  (16384 + (j) * 8192)     // [32][128] f16, pitch 256B (3 x 8 KiB)
#define T2B    40960                    // [32][128] f16, pitch 256B (8 KiB)
#define MB(j)  ((j) == 2 ? T2B : (STA + (j) * 8192))
#define LDS_BYTES 49152

__device__ __forceinline__ f16x8 afrag(const unsigned char* lds, int base, int pitchh,
                                       int row0, int k0, int lr, int lg) {
    int row = row0 + lr;
    int off = base + row * (pitchh * 2) + (((k0 + (lg << 3)) * 2) ^ ((row & 7) << 4));
    return *(const f16x8*)(lds + off);
}
__device__ __forceinline__ f16x4 ldsv4(const unsigned char* lds, int base, int pitchh,
                                       int row, int col) {
    int off = base + row * (pitchh * 2) + ((col * 2) ^ ((row & 7) << 4));
    return *(const f16x4*)(lds + off);
}
__device__ __forceinline__ void stsv4(unsigned char* lds, int base, int pitchh,
                                      int row, int col, f16x4 v) {
    int off = base + row * (pitchh * 2) + ((col * 2) ^ ((row & 7) << 4));
    *(f16x4*)(lds + off) = v;
}
__device__ __forceinline__ void ldss(unsigned char* lds, int base, int pitchh,
                                     int row, int col, float v) {
    int off = base + row * (pitchh * 2) + ((col * 2) ^ ((row & 7) << 4));
    *(f16*)(lds + off) = (f16)v;
}
__device__ __forceinline__ f16x8 wfrag(const f16* __restrict__ panel, int rt16, int kb,
                                       int rb, int lane) {
    return *(const f16x8*)(panel + (size_t)((kb * rt16 + rb) * 512 + lane * 8));
}

__global__ __launch_bounds__(256, 3)
void node_tp(const float* __restrict__ nf, const f16* __restrict__ wp,
             float* __restrict__ out, int n_nodes) {
    __shared__ __align__(16) unsigned char lds[LDS_BYTES];
    const int tid = threadIdx.x;       // 0..255
    const int lane = tid & 63;
    const int wv = tid >> 6;           // 0..3
    const int z0 = blockIdx.x * NT;
    const int nvalid = min(NT, n_nodes - z0);
    const int lr = lane & 15;
    const int lg = lane >> 4;

    const f16* w00p  = wp;
    const f16* w01p  = wp + 65536;
    const f16* w10p  = wp + 98304;
    const f16* w110p = wp + 131072;
    const f16* w111p = wp + 147456;
    const f16* W0ep  = wp + 163840;
    const f16* W1op  = wp + 262144;
    const f16* W1ep  = wp + 311296;

    const float C000 = 0.0625f;               // 1/sqrt(256)
    const float C011 = 0.08838834764831843f;  // 1/sqrt(128)
    const float C101 = 0.0625f;
    const float C110 = 0.05103103630798287f;  // 1/sqrt(384)
    const float C111 = 0.0625f;               // 1/16
    const float RS384 = 0.05103103630798287f;
    const float RS128 = 0.08838834764831843f;

    // ---- P0: stage node_feat -> LDS (swizzled, [node][channel]) ----
    #pragma unroll 5
    for (int q = tid; q < NT * 160; q += 256) {
        int row = q / 160;
        int c4 = q - row * 160;
        float4 v4 = make_float4(0.f, 0.f, 0.f, 0.f);
        if (row < nvalid)
            v4 = ((const float4*)(nf + (size_t)(z0 + row) * 640))[c4];
        int c = c4 * 4;
        if (c < 256) {
            f16x4 h = {(f16)v4.x, (f16)v4.y, (f16)v4.z, (f16)v4.w};
            int off = STA + row * 512 + ((c * 2) ^ ((row & 7) << 4));
            *(f16x4*)(lds + off) = h;
        } else {
            float vv[4] = {v4.x, v4.y, v4.z, v4.w};
            #pragma unroll
            for (int e = 0; e < 4; ++e) {
                int m = c - 256 + e;
                int u = m / 3;
                int j = m - u * 3;
                ldss(lds, VB(j), 128, row, u, vv[e]);
            }
        }
    }
    // s for p1/p2 epilogues in registers. ch = (wv+4h)*32 + rt*16 + lg*4
    f16x4 s4r[2][2][2];  // [h][rt][nt]
    #pragma unroll
    for (int h = 0; h < 2; ++h)
        #pragma unroll
        for (int rt = 0; rt < 2; ++rt)
            #pragma unroll
            for (int nt = 0; nt < 2; ++nt) {
                int node = nt * 16 + lr;
                float4 f = make_float4(0.f, 0.f, 0.f, 0.f);
                if (node < nvalid)
                    f = *(const float4*)(nf + (size_t)(z0 + node) * 640 +
                                         (wv + 4 * h) * 32 + rt * 16 + lg * 4);
                s4r[h][rt][nt] = f16x4{(f16)f.x, (f16)f.y, (f16)f.z, (f16)f.w};
            }
    barrier_lds();

    // ---- P1: A1^T = w00 @ S^T (merged-h, shared b, rolled 1-deep prefetch) ----
    f32x4 acc1[2][2][2] = {};  // [h][rt][nt]
    {
        f16x8 a00 = wfrag(w00p, 16, 0, 2 * wv, lane);
        f16x8 a01 = wfrag(w00p, 16, 0, 2 * wv + 1, lane);
        f16x8 a10 = wfrag(w00p, 16, 0, 2 * (wv + 4), lane);
        f16x8 a11 = wfrag(w00p, 16, 0, 2 * (wv + 4) + 1, lane);
        #pragma unroll 1
        for (int ks = 0; ks < 8; ++ks) {
            int kn = ks + 1 < 8 ? ks + 1 : ks;
            f16x8 n00 = wfrag(w00p, 16, kn, 2 * wv, lane);
            f16x8 n01 = wfrag(w00p, 16, kn, 2 * wv + 1, lane);
            f16x8 n10 = wfrag(w00p, 16, kn, 2 * (wv + 4), lane);
            f16x8 n11 = wfrag(w00p, 16, kn, 2 * (wv + 4) + 1, lane);
            f16x8 b0 = afrag(lds, STA, 256, 0, ks * 32, lr, lg);
            f16x8 b1 = afrag(lds, STA, 256, 16, ks * 32, lr, lg);
            acc1[0][0][0] = MFMA16(a00, b0, acc1[0][0][0]);
            acc1[0][0][1] = MFMA16(a00, b1, acc1[0][0][1]);
            acc1[0][1][0] = MFMA16(a01, b0, acc1[0][1][0]);
            acc1[0][1][1] = MFMA16(a01, b1, acc1[0][1][1]);
            acc1[1][0][0] = MFMA16(a10, b0, acc1[1][0][0]);
            acc1[1][0][1] = MFMA16(a10, b1, acc1[1][0][1]);
            acc1[1][1][0] = MFMA16(a11, b0, acc1[1][1][0]);
            acc1[1][1][1] = MFMA16(a11, b1, acc1[1][1][1]);
            a00 = n00; a01 = n01; a10 = n10; a11 = n11;
        }
    }
    // ---- P4: A3^T = w10 @ S^T (merged-h: g shared, b per node-tile) ----
    f32x4 acc3[2][2] = {};  // [h][r2]
    {
        f16x8 g0 = wfrag(w10p, 8, 0, 2 * wv, lane);
        f16x8 g1 = wfrag(w10p, 8, 0, 2 * wv + 1, lane);
        #pragma unroll 1
        for (int ks = 0; ks < 8; ++ks) {
            int kn = ks + 1 < 8 ? ks + 1 : ks;
            f16x8 n0 = wfrag(w10p, 8, kn, 2 * wv, lane);
            f16x8 n1 = wfrag(w10p, 8, kn, 2 * wv + 1, lane);
            f16x8 b0 = afrag(lds, STA, 256, 0, ks * 32, lr, lg);
            f16x8 b1 = afrag(lds, STA, 256, 16, ks * 32, lr, lg);
            acc3[0][0] = MFMA16(g0, b0, acc3[0][0]);
            acc3[0][1] = MFMA16(g1, b0, acc3[0][1]);
            acc3[1][0] = MFMA16(g0, b1, acc3[1][0]);
            acc3[1][1] = MFMA16(g1, b1, acc3[1][1]);
            g0 = n0; g1 = n1;
        }
    }
    // ---- P2: A4j^T = w110 @ Vj^T ; p4 -> T2B (per h) ----
    #pragma unroll
    for (int h = 0; h < 2; ++h) {
        f32x4 a4[3][2] = {};  // [j][r2]
        #pragma unroll
        for (int ks = 0; ks < 4; ++ks) {
            f16x8 h0 = wfrag(w110p, 8, ks, 2 * wv, lane);
            f16x8 h1 = wfrag(w110p, 8, ks, 2 * wv + 1, lane);
            #pragma unroll
            for (int j = 0; j < 3; ++j) {
                f16x8 b = afrag(lds, VB(j), 128, h * 16, ks * 32, lr, lg);
                a4[j][0] = MFMA16(h0, b, a4[j][0]);
                a4[j][1] = MFMA16(h1, b, a4[j][1]);
            }
        }
        #pragma unroll
        for (int r2 = 0; r2 < 2; ++r2) {
            int node = h * 16 + lr;
            int u0 = (2 * wv + r2) * 16 + lg * 4;
            float p4[4] = {0.f, 0.f, 0.f, 0.f};
            #pragma unroll
            for (int j = 0; j < 3; ++j) {
                f16x4 v4 = ldsv4(lds, VB(j), 128, node, u0);
                #pragma unroll
                for (int r = 0; r < 4; ++r)
                    p4[r] += (float)v4[r] * a4[j][r2][r];
            }
            f16x4 t4;
            #pragma unroll
            for (int r = 0; r < 4; ++r) t4[r] = (f16)(C110 * p4[r]);
            stsv4(lds, T2B, 128, node, u0, t4);
        }
    }
    barrier_lds();  // all S reads done -> STA writable

    // p1 = C000 * s(regs) * A1 -> STA in place (becomes T[:,0:256])
    #pragma unroll
    for (int h = 0; h < 2; ++h)
        #pragma unroll
        for (int rt = 0; rt < 2; ++rt)
            #pragma unroll
            for (int nt = 0; nt < 2; ++nt) {
                f16x4 t4;
                #pragma unroll
                for (int r = 0; r < 4; ++r)
                    t4[r] = (f16)(C000 * (float)s4r[h][rt][nt][r] * acc1[h][rt][nt][r]);
                stsv4(lds, STA, 256, nt * 16 + lr, (wv + 4 * h) * 32 + rt * 16 + lg * 4, t4);
            }
    barrier_lds();  // T = [STA|T2B] ready

    // ---- P3: out_0e^T = W0e^T @ T^T / sqrt(384) (merged-h, rolled, region-switch) ----
    {
        f32x4 acc[2][2][2] = {};  // [h][rt][nt]
        f16x8 a00 = wfrag(W0ep, 16, 0, 2 * wv, lane);
        f16x8 a01 = wfrag(W0ep, 16, 0, 2 * wv + 1, lane);
        f16x8 a10 = wfrag(W0ep, 16, 0, 2 * (wv + 4), lane);
        f16x8 a11 = wfrag(W0ep, 16, 0, 2 * (wv + 4) + 1, lane);
        #pragma unroll 1
        for (int ks = 0; ks < 12; ++ks) {
            int kn = ks + 1 < 12 ? ks + 1 : ks;
            f16x8 n00 = wfrag(W0ep, 16, kn, 2 * wv, lane);
            f16x8 n01 = wfrag(W0ep, 16, kn, 2 * wv + 1, lane);
            f16x8 n10 = wfrag(W0ep, 16, kn, 2 * (wv + 4), lane);
            f16x8 n11 = wfrag(W0ep, 16, kn, 2 * (wv + 4) + 1, lane);
            f16x8 b0 = (ks < 8) ? afrag(lds, STA, 256, 0, ks * 32, lr, lg)
                                : afrag(lds, T2B, 128, 0, (ks - 8) * 32, lr, lg);
            f16x8 b1 = (ks < 8) ? afrag(lds, STA, 256, 16, ks * 32, lr, lg)
                                : afrag(lds, T2B, 128, 16, (ks - 8) * 32, lr, lg);
            acc[0][0][0] = MFMA16(a00, b0, acc[0][0][0]);
            acc[0][0][1] = MFMA16(a00, b1, acc[0][0][1]);
            acc[0][1][0] = MFMA16(a01, b0, acc[0][1][0]);
            acc[0][1][1] = MFMA16(a01, b1, acc[0][1][1]);
            acc[1][0][0] = MFMA16(a10, b0, acc[1][0][0]);
            acc[1][0][1] = MFMA16(a10, b1, acc[1][0][1]);
            acc[1][1][0] = MFMA16(a11, b0, acc[1][1][0]);
            acc[1][1][1] = MFMA16(a11, b1, acc[1][1][1]);
            a00 = n00; a01 = n01; a10 = n10; a11 = n11;
        }
        #pragma unroll
        for (int h = 0; h < 2; ++h)
            #pragma unroll
            for (int rt = 0; rt < 2; ++rt)
                #pragma unroll
                for (int nt = 0; nt < 2; ++nt) {
                    int node = nt * 16 + lr;
                    if (node < nvalid) {
                        int o = (wv + 4 * h) * 32 + rt * 16 + lg * 4;
                        float4 o4;
                        o4.x = RS384 * acc[h][rt][nt][0];
                        o4.y = RS384 * acc[h][rt][nt][1];
                        o4.z = RS384 * acc[h][rt][nt][2];
                        o4.w = RS384 * acc[h][rt][nt][3];
                        *(float4*)(&out[(size_t)(z0 + node) * 1024 + o]) = o4;
                    }
                }
    }

    // ---- P5 (j-loop): A2j -> p2 (STA); p3 from acc3 regs (T2B); out1o += W1o^T @ T^T ----
    f32x4 acc1o[2][2][3] = {};  // [h][r2][j]
    #pragma unroll
    for (int j = 0; j < 3; ++j) {
        f32x4 a2[2][2][2] = {};  // [h][rt][nt] (computed per-h to bound pressure)
        #pragma unroll
        for (int h = 0; h < 2; ++h)
            #pragma unroll
            for (int ks = 0; ks < 4; ++ks) {
                f16x8 a0 = wfrag(w01p, 16, ks, 2 * (wv + 4 * h), lane);
                f16x8 a1 = wfrag(w01p, 16, ks, 2 * (wv + 4 * h) + 1, lane);
                #pragma unroll
                for (int nt = 0; nt < 2; ++nt) {
                    f16x8 b = afrag(lds, VB(j), 128, nt * 16, ks * 32, lr, lg);
                    a2[h][0][nt] = MFMA16(a0, b, a2[h][0][nt]);
                    a2[h][1][nt] = MFMA16(a1, b, a2[h][1][nt]);
                }
            }
        barrier_lds();  // previous T readers (P3 or W1o_{j-1}) done
        #pragma unroll
        for (int h = 0; h < 2; ++h)
            #pragma unroll
            for (int rt = 0; rt < 2; ++rt)
                #pragma unroll
                for (int nt = 0; nt < 2; ++nt) {
                    f16x4 t4;
                    #pragma unroll
                    for (int r = 0; r < 4; ++r)
                        t4[r] = (f16)(C011 * (float)s4r[h][rt][nt][r] * a2[h][rt][nt][r]);
                    stsv4(lds, STA, 256, nt * 16 + lr, (wv + 4 * h) * 32 + rt * 16 + lg * 4, t4);
                }
        #pragma unroll
        for (int h = 0; h < 2; ++h)
            #pragma unroll
            for (int r2 = 0; r2 < 2; ++r2) {
                f16x4 v4 = ldsv4(lds, VB(j), 128, h * 16 + lr, (2 * wv + r2) * 16 + lg * 4);
                f16x4 t4;
                #pragma unroll
                for (int r = 0; r < 4; ++r)
                    t4[r] = (f16)(C101 * (float)v4[r] * acc3[h][r2][r]);
                stsv4(lds, T2B, 128, h * 16 + lr, (2 * wv + r2) * 16 + lg * 4, t4);
            }
        barrier_lds();  // [p2|p3] ready
        {
            f16x8 a0 = wfrag(W1op, 8, 0, 2 * wv, lane);
            f16x8 a1 = wfrag(W1op, 8, 0, 2 * wv + 1, lane);
            #pragma unroll 1
            for (int ks = 0; ks < 12; ++ks) {
                int kn = ks + 1 < 12 ? ks + 1 : ks;
                f16x8 n0 = wfrag(W1op, 8, kn, 2 * wv, lane);
                f16x8 n1 = wfrag(W1op, 8, kn, 2 * wv + 1, lane);
                f16x8 b0 = (ks < 8) ? afrag(lds, STA, 256, 0, ks * 32, lr, lg)
                                    : afrag(lds, T2B, 128, 0, (ks - 8) * 32, lr, lg);
                f16x8 b1 = (ks < 8) ? afrag(lds, STA, 256, 16, ks * 32, lr, lg)
                                    : afrag(lds, T2B, 128, 16, (ks - 8) * 32, lr, lg);
                acc1o[0][0][j] = MFMA16(a0, b0, acc1o[0][0][j]);
                acc1o[0][1][j] = MFMA16(a1, b0, acc1o[0][1][j]);
                acc1o[1][0][j] = MFMA16(a0, b1, acc1o[1][0][j]);
                acc1o[1][1][j] = MFMA16(a1, b1, acc1o[1][1][j]);
                a0 = n0; a1 = n1;
            }
        }
    }
    barrier_lds();  // last W1o reads done -> STA/T2B writable for M

    // out_1o store (registers only)
    #pragma unroll
    for (int h = 0; h < 2; ++h)
        #pragma unroll
        for (int r2 = 0; r2 < 2; ++r2) {
            int node = h * 16 + lr;
            if (node < nvalid) {
                int o0 = (2 * wv + r2) * 16 + lg * 4;
                float vals[12];
                #pragma unroll
                for (int r = 0; r < 4; ++r)
                    #pragma unroll
                    for (int j = 0; j < 3; ++j)
                        vals[r * 3 + j] = RS384 * acc1o[h][r2][j][r];
                size_t base = (size_t)(z0 + node) * 1024 + 256 + 3 * o0;
                #pragma unroll
                for (int qq = 0; qq < 3; ++qq) {
                    float4 f;
                    f.x = vals[qq * 4 + 0]; f.y = vals[qq * 4 + 1];
                    f.z = vals[qq * 4 + 2]; f.w = vals[qq * 4 + 3];
                    *(float4*)(&out[base + qq * 4]) = f;
                }
            }
        }

    // ---- P6: M_j = w111 @ V_j^T -> M planes (merged-h: weights shared) ----
    #pragma unroll
    for (int j = 0; j < 3; ++j) {
        f32x4 am[2][2] = {};  // [h][r2]
        #pragma unroll
        for (int ks = 0; ks < 4; ++ks) {
            f16x8 h0 = wfrag(w111p, 8, ks, 2 * wv, lane);
            f16x8 h1 = wfrag(w111p, 8, ks, 2 * wv + 1, lane);
            f16x8 b0 = afrag(lds, VB(j), 128, 0, ks * 32, lr, lg);
            f16x8 b1 = afrag(lds, VB(j), 128, 16, ks * 32, lr, lg);
            am[0][0] = MFMA16(h0, b0, am[0][0]);
            am[0][1] = MFMA16(h1, b0, am[0][1]);
            am[1][0] = MFMA16(h0, b1, am[1][0]);
            am[1][1] = MFMA16(h1, b1, am[1][1]);
        }
        #pragma unroll
        for (int h = 0; h < 2; ++h)
            #pragma unroll
            for (int r2 = 0; r2 < 2; ++r2) {
                f16x4 t4;
                #pragma unroll
                for (int r = 0; r < 4; ++r) t4[r] = (f16)am[h][r2][r];
                stsv4(lds, MB(j), 128, h * 16 + lr, (2 * wv + r2) * 16 + lg * 4, t4);
            }
    }
    barrier_lds();  // M visible

    // ---- cross: p5_j -> V planes in place ----
    #pragma unroll 1
    for (int q = tid; q < NT * 32; q += 256) {
        int row = q >> 5;
        int col = (q & 31) * 4;
        f16x4 v0 = ldsv4(lds, VB(0), 128, row, col);
        f16x4 v1 = ldsv4(lds, VB(1), 128, row, col);
        f16x4 v2 = ldsv4(lds, VB(2), 128, row, col);
        f16x4 m0 = ldsv4(lds, MB(0), 128, row, col);
        f16x4 m1 = ldsv4(lds, MB(1), 128, row, col);
        f16x4 m2 = ldsv4(lds, MB(2), 128, row, col);
        f16x4 c0, c1, c2;
        #pragma unroll
        for (int r = 0; r < 4; ++r) {
            c0[r] = (f16)(C111 * ((float)v1[r] * (float)m2[r] - (float)v2[r] * (float)m1[r]));
            c1[r] = (f16)(C111 * ((float)v2[r] * (float)m0[r] - (float)v0[r] * (float)m2[r]));
            c2[r] = (f16)(C111 * ((float)v0[r] * (float)m1[r] - (float)v1[r] * (float)m0[r]));
        }
        stsv4(lds, VB(0), 128, row, col, c0);
        stsv4(lds, VB(1), 128, row, col, c1);
        stsv4(lds, VB(2), 128, row, col, c2);
    }
    barrier_lds();  // p5 ready

    // ---- P7: out_1e = W1e^T @ p5^T / sqrt(128) (merged-h) ----
    {
        f32x4 acc[2][2][3] = {};  // [h][r2][j]
        #pragma unroll
        for (int j = 0; j < 3; ++j)
            #pragma unroll
            for (int ks = 0; ks < 4; ++ks) {
                f16x8 a0 = wfrag(W1ep, 8, ks, 2 * wv, lane);
                f16x8 a1 = wfrag(W1ep, 8, ks, 2 * wv + 1, lane);
                f16x8 b0 = afrag(lds, VB(j), 128, 0, ks * 32, lr, lg);
                f16x8 b1 = afrag(lds, VB(j), 128, 16, ks * 32, lr, lg);
                acc[0][0][j] = MFMA16(a0, b0, acc[0][0][j]);
                acc[0][1][j] = MFMA16(a1, b0, acc[0][1][j]);
                acc[1][0][j] = MFMA16(a0, b1, acc[1][0][j]);
                acc[1][1][j] = MFMA16(a1, b1, acc[1][1][j]);
            }
        #pragma unroll
        for (int h = 0; h < 2; ++h)
            #pragma unroll
            for (int r2 = 0; r2 < 2; ++r2) {
                int node = h * 16 + lr;
                if (node < nvalid) {
                    int o0 = (2 * wv + r2) * 16 + lg * 4;
                    float vals[12];
                    #pragma unroll
                    for (int r = 0; r < 4; ++r)
                        #pragma unroll
                        for (int j = 0; j < 3; ++j)
                            vals[r * 3 + j] = RS128 * acc[h][r2][j][r];
                    size_t base = (size_t)(z0 + node) * 1024 + 640 + 3 * o0;
                    #pragma unroll
                    for (int qq = 0; qq < 3; ++qq) {
                        float4 f;
                        f.x = vals[qq * 4 + 0]; f.y = vals[qq * 4 + 1];
                        f.z = vals[qq * 4 + 2]; f.w = vals[qq * 4 + 3];
                        *(float4*)(&out[base + qq * 4]) = f;
                    }
                }
            }
    }
}

extern "C" void kernel_launch(void* const* d_in, const int* in_sizes, int n_in,
                              void* d_out, int out_size, void* d_ws, size_t ws_size,
                              hipStream_t stream) {
    const float* nf   = (const float*)d_in[0];
    const float* w00  = (const float*)d_in[1];
    const float* w01  = (const float*)d_in[2];
    const float* w10  = (const float*)d_in[3];
    const float* w110 = (const float*)d_in[4];
    const float* w111 = (const float*)d_in[5];
    const float* W0e  = (const float*)d_in[6];
    const float* W1o  = (const float*)d_in[7];
    const float* W1e  = (const float*)d_in[8];
    f16* wpack = (f16*)d_ws;  // needs 655,360 bytes

    int n_nodes = in_sizes[0] / 640;
    pack_weights<<<1280, 256, 0, stream>>>(w00, w01, w10, w110, w111, W0e, W1o, W1e, wpack);
    int blocks = (n_nodes + NT - 1) / NT;
    node_tp<<<blocks, 256, 0, stream>>>(nf, wpack, (float*)d_out, n_nodes);
}

// Round 10
// 235.251 us; speedup vs baseline: 1.1295x; 1.0127x over previous
//
#include <hip/hip_runtime.h>

typedef _Float16 f16;
typedef _Float16 f16x8 __attribute__((ext_vector_type(8)));
typedef _Float16 f16x4 __attribute__((ext_vector_type(4)));
typedef float f32x4 __attribute__((ext_vector_type(4)));

#define MFMA16(a, b, c) __builtin_amdgcn_mfma_f32_16x16x32_f16(a, b, c, 0, 0, 0)

// LDS-only barrier: drains LDS ops but leaves global loads/stores in flight.
// Legal: every barrier here protects only LDS data (weights read-only, out write-only).
__device__ __forceinline__ void barrier_lds() {
    asm volatile("s_waitcnt lgkmcnt(0)" ::: "memory");
    __builtin_amdgcn_s_barrier();
}

// ---------------- weight packing (A-operand layout) ----------------
__device__ __forceinline__ void pack_one(int local, const float* __restrict__ src,
                                         f16* __restrict__ dst, int K, int R, int transpose) {
    int i = local & 7;
    int l = (local >> 3) & 63;
    int p = local >> 9;
    int rt16 = R >> 4;
    int rb = p % rt16;
    int kb = p / rt16;
    int k = kb * 32 + ((l >> 4) << 3) + i;
    int r = rb * 16 + (l & 15);
    float v = transpose ? src[k * R + r] : src[r * K + k];
    dst[local] = (f16)v;
}

__global__ void pack_weights(const float* __restrict__ w00, const float* __restrict__ w01,
                             const float* __restrict__ w10, const float* __restrict__ w110,
                             const float* __restrict__ w111, const float* __restrict__ W0e,
                             const float* __restrict__ W1o, const float* __restrict__ W1e,
                             f16* __restrict__ dst) {
    int idx = blockIdx.x * 256 + threadIdx.x;
    if (idx < 65536)        pack_one(idx,          w00,  dst,          256, 256, 0);
    else if (idx < 98304)   pack_one(idx - 65536,  w01,  dst + 65536,  128, 256, 0);
    else if (idx < 131072)  pack_one(idx - 98304,  w10,  dst + 98304,  256, 128, 0);
    else if (idx < 147456)  pack_one(idx - 131072, w110, dst + 131072, 128, 128, 0);
    else if (idx < 163840)  pack_one(idx - 147456, w111, dst + 147456, 128, 128, 0);
    else if (idx < 262144)  pack_one(idx - 163840, W0e,  dst + 163840, 384, 256, 1);
    else if (idx < 311296)  pack_one(idx - 262144, W1o,  dst + 262144, 384, 128, 1);
    else                    pack_one(idx - 311296, W1e,  dst + 311296, 128, 128, 1);
}

// ---------------- main fused kernel ----------------
// NT=16, 4-wave (256-thread) blocks, r5 map scaled to 36 KiB -> 4 blocks/CU.
// Same per-wave work as r5 (the r9 mistake was doubling it), same 16 waves/CU,
// but 4 independent sync domains instead of 2: within-block lockstep halves,
// cross-block phase diversity doubles. VGPR budget 128 (4 waves/SIMD) - safe.
#define NT 16
#define STA      0                      // [16][256] f16, pitch 512B (8 KiB)
#define VB(j)    (8192 + (j) * 4096)    // [16][128] f16, pitch 256B (3 x 4 KiB)
#define TB       20480                  // [16][384] f16, pitch 768B (12 KiB)
#define A3B      32768                  // [16][128] f16, pitch 256B (4 KiB)
#define MBASE(j) (TB + (j) * 4096)      // reuse T as three [16][128] planes
#define P5BASE(j) ((j) == 0 ? A3B : (STA + ((j) - 1) * 4096))
#define LDS_BYTES 36864

__device__ __forceinline__ f16x8 afrag(const unsigned char* lds, int base, int pitchh,
                                       int row0, int k0, int lr, int lg) {
    int row = row0 + lr;
    int off = base + row * (pitchh * 2) + (((k0 + (lg << 3)) * 2) ^ ((row & 7) << 4));
    return *(const f16x8*)(lds + off);
}
__device__ __forceinline__ f16x4 ldsv4(const unsigned char* lds, int base, int pitchh,
                                       int row, int col) {
    int off = base + row * (pitchh * 2) + ((col * 2) ^ ((row & 7) << 4));
    return *(const f16x4*)(lds + off);
}
__device__ __forceinline__ void stsv4(unsigned char* lds, int base, int pitchh,
                                      int row, int col, f16x4 v) {
    int off = base + row * (pitchh * 2) + ((col * 2) ^ ((row & 7) << 4));
    *(f16x4*)(lds + off) = v;
}
__device__ __forceinline__ void ldss(unsigned char* lds, int base, int pitchh,
                                     int row, int col, float v) {
    int off = base + row * (pitchh * 2) + ((col * 2) ^ ((row & 7) << 4));
    *(f16*)(lds + off) = (f16)v;
}
__device__ __forceinline__ f16x8 wfrag(const f16* __restrict__ panel, int rt16, int kb,
                                       int rb, int lane) {
    return *(const f16x8*)(panel + (size_t)((kb * rt16 + rb) * 512 + lane * 8));
}

__global__ __launch_bounds__(256, 4)
void node_tp(const float* __restrict__ nf, const f16* __restrict__ wp,
             float* __restrict__ out, int n_nodes) {
    __shared__ __align__(16) unsigned char lds[LDS_BYTES];
    const int tid = threadIdx.x;   // 0..255
    const int lane = tid & 63;
    const int wv = tid >> 6;       // 0..3
    const int z0 = blockIdx.x * NT;
    const int nvalid = min(NT, n_nodes - z0);
    const int lr = lane & 15;      // node index within tile
    const int lg = lane >> 4;

    const f16* w00p  = wp;
    const f16* w01p  = wp + 65536;
    const f16* w10p  = wp + 98304;
    const f16* w110p = wp + 131072;
    const f16* w111p = wp + 147456;
    const f16* W0ep  = wp + 163840;
    const f16* W1op  = wp + 262144;
    const f16* W1ep  = wp + 311296;

    const float C000 = 0.0625f;               // 1/sqrt(256)
    const float C011 = 0.08838834764831843f;  // 1/sqrt(128)
    const float C101 = 0.0625f;
    const float C110 = 0.05103103630798287f;  // 1/sqrt(384)
    const float C111 = 0.0625f;               // 1/16
    const float RS384 = 0.05103103630798287f;
    const float RS128 = 0.08838834764831843f;

    // ---- P0: stage node_feat -> LDS (swizzled, [node][channel]) ----
    #pragma unroll 5
    for (int q = tid; q < NT * 160; q += 256) {
        int row = q / 160;
        int c4 = q - row * 160;
        float4 v4 = make_float4(0.f, 0.f, 0.f, 0.f);
        if (row < nvalid)
            v4 = ((const float4*)(nf + (size_t)(z0 + row) * 640))[c4];
        int c = c4 * 4;
        if (c < 256) {
            f16x4 h = {(f16)v4.x, (f16)v4.y, (f16)v4.z, (f16)v4.w};
            int off = STA + row * 512 + ((c * 2) ^ ((row & 7) << 4));
            *(f16x4*)(lds + off) = h;
        } else {
            float vv[4] = {v4.x, v4.y, v4.z, v4.w};
            #pragma unroll
            for (int e = 0; e < 4; ++e) {
                int m = c - 256 + e;
                int u = m / 3;
                int j = m - u * 3;
                ldss(lds, VB(j), 128, row, u, vv[e]);
            }
        }
    }
    // s for p1/p2 epilogues in registers: s[node=lr][wv*64 + c*16 + lg*4 ..+3]
    f16x4 s4r[4];
    #pragma unroll
    for (int c = 0; c < 4; ++c) {
        float4 f = make_float4(0.f, 0.f, 0.f, 0.f);
        if (lr < nvalid)
            f = *(const float4*)(nf + (size_t)(z0 + lr) * 640 + wv * 64 + c * 16 + lg * 4);
        s4r[c] = f16x4{(f16)f.x, (f16)f.y, (f16)f.z, (f16)f.w};
    }
    barrier_lds();

    // ---- P1: A1^T = w00 @ S^T (4 ch-tiles/wave, shared b, rolled 1-deep prefetch) ----
    f32x4 acc1[4] = {};
    {
        f16x8 a0 = wfrag(w00p, 16, 0, 4 * wv + 0, lane);
        f16x8 a1 = wfrag(w00p, 16, 0, 4 * wv + 1, lane);
        f16x8 a2 = wfrag(w00p, 16, 0, 4 * wv + 2, lane);
        f16x8 a3 = wfrag(w00p, 16, 0, 4 * wv + 3, lane);
        #pragma unroll 1
        for (int ks = 0; ks < 8; ++ks) {
            int kn = ks + 1 < 8 ? ks + 1 : ks;
            f16x8 n0 = wfrag(w00p, 16, kn, 4 * wv + 0, lane);
            f16x8 n1 = wfrag(w00p, 16, kn, 4 * wv + 1, lane);
            f16x8 n2 = wfrag(w00p, 16, kn, 4 * wv + 2, lane);
            f16x8 n3 = wfrag(w00p, 16, kn, 4 * wv + 3, lane);
            f16x8 b = afrag(lds, STA, 256, 0, ks * 32, lr, lg);
            acc1[0] = MFMA16(a0, b, acc1[0]);
            acc1[1] = MFMA16(a1, b, acc1[1]);
            acc1[2] = MFMA16(a2, b, acc1[2]);
            acc1[3] = MFMA16(a3, b, acc1[3]);
            a0 = n0; a1 = n1; a2 = n2; a3 = n3;
        }
        #pragma unroll
        for (int c = 0; c < 4; ++c) {
            f16x4 t4;
            #pragma unroll
            for (int r = 0; r < 4; ++r)
                t4[r] = (f16)(C000 * (float)s4r[c][r] * acc1[c][r]);
            stsv4(lds, TB, 384, lr, wv * 64 + c * 16 + lg * 4, t4);
        }
    }
    // ---- P2: A4j^T = w110 @ Vj^T ; p4 = C110*sum_j Vj*A4j -> T[:,256:384] ----
    {
        f32x4 a4[3][2] = {};  // [j][r2], ch-tiles 2wv, 2wv+1
        #pragma unroll
        for (int ks = 0; ks < 4; ++ks) {
            f16x8 h0 = wfrag(w110p, 8, ks, 2 * wv, lane);
            f16x8 h1 = wfrag(w110p, 8, ks, 2 * wv + 1, lane);
            #pragma unroll
            for (int j = 0; j < 3; ++j) {
                f16x8 b = afrag(lds, VB(j), 128, 0, ks * 32, lr, lg);
                a4[j][0] = MFMA16(h0, b, a4[j][0]);
                a4[j][1] = MFMA16(h1, b, a4[j][1]);
            }
        }
        #pragma unroll
        for (int r2 = 0; r2 < 2; ++r2) {
            int u0 = (2 * wv + r2) * 16 + lg * 4;
            float p4[4] = {0.f, 0.f, 0.f, 0.f};
            #pragma unroll
            for (int j = 0; j < 3; ++j) {
                f16x4 v4 = ldsv4(lds, VB(j), 128, lr, u0);
                #pragma unroll
                for (int r = 0; r < 4; ++r)
                    p4[r] += (float)v4[r] * a4[j][r2][r];
            }
            f16x4 t4;
            #pragma unroll
            for (int r = 0; r < 4; ++r) t4[r] = (f16)(C110 * p4[r]);
            stsv4(lds, TB, 384, lr, 256 + u0, t4);
        }
    }
    barrier_lds();

    // ---- P3: out_0e^T = W0e^T @ T^T / sqrt(384) (4 ch-tiles/wave, rolled) ----
    {
        f32x4 acc[4] = {};
        f16x8 a0 = wfrag(W0ep, 16, 0, 4 * wv + 0, lane);
        f16x8 a1 = wfrag(W0ep, 16, 0, 4 * wv + 1, lane);
        f16x8 a2 = wfrag(W0ep, 16, 0, 4 * wv + 2, lane);
        f16x8 a3 = wfrag(W0ep, 16, 0, 4 * wv + 3, lane);
        #pragma unroll 1
        for (int ks = 0; ks < 12; ++ks) {
            int kn = ks + 1 < 12 ? ks + 1 : ks;
            f16x8 n0 = wfrag(W0ep, 16, kn, 4 * wv + 0, lane);
            f16x8 n1 = wfrag(W0ep, 16, kn, 4 * wv + 1, lane);
            f16x8 n2 = wfrag(W0ep, 16, kn, 4 * wv + 2, lane);
            f16x8 n3 = wfrag(W0ep, 16, kn, 4 * wv + 3, lane);
            f16x8 b = afrag(lds, TB, 384, 0, ks * 32, lr, lg);
            acc[0] = MFMA16(a0, b, acc[0]);
            acc[1] = MFMA16(a1, b, acc[1]);
            acc[2] = MFMA16(a2, b, acc[2]);
            acc[3] = MFMA16(a3, b, acc[3]);
            a0 = n0; a1 = n1; a2 = n2; a3 = n3;
        }
        if (lr < nvalid) {
            #pragma unroll
            for (int c = 0; c < 4; ++c) {
                int o = wv * 64 + c * 16 + lg * 4;
                float4 o4;
                o4.x = RS384 * acc[c][0];
                o4.y = RS384 * acc[c][1];
                o4.z = RS384 * acc[c][2];
                o4.w = RS384 * acc[c][3];
                *(float4*)(&out[(size_t)(z0 + lr) * 1024 + o]) = o4;
            }
        }
    }
    // ---- P4: A3^T = w10 @ S^T -> A3B (2 ch-tiles/wave, rolled) ----
    {
        f32x4 acc3[2] = {};
        f16x8 a0 = wfrag(w10p, 8, 0, 2 * wv, lane);
        f16x8 a1 = wfrag(w10p, 8, 0, 2 * wv + 1, lane);
        #pragma unroll 1
        for (int ks = 0; ks < 8; ++ks) {
            int kn = ks + 1 < 8 ? ks + 1 : ks;
            f16x8 n0 = wfrag(w10p, 8, kn, 2 * wv, lane);
            f16x8 n1 = wfrag(w10p, 8, kn, 2 * wv + 1, lane);
            f16x8 b = afrag(lds, STA, 256, 0, ks * 32, lr, lg);
            acc3[0] = MFMA16(a0, b, acc3[0]);
            acc3[1] = MFMA16(a1, b, acc3[1]);
            a0 = n0; a1 = n1;
        }
        #pragma unroll
        for (int r2 = 0; r2 < 2; ++r2) {
            f16x4 t4;
            #pragma unroll
            for (int r = 0; r < 4; ++r) t4[r] = (f16)acc3[r2][r];
            stsv4(lds, A3B, 128, lr, (2 * wv + r2) * 16 + lg * 4, t4);
        }
    }
    barrier_lds();

    // ---- P5: for j: {A2j -> p2 -> T[:,0:256]; p3 -> T[:,256:384]; out1o += W1o^T@T^T} ----
    f32x4 acc1o[2][3] = {};  // [r2][j]
    #pragma unroll
    for (int j = 0; j < 3; ++j) {
        {
            f32x4 a2[4] = {};
            #pragma unroll
            for (int ks = 0; ks < 4; ++ks) {
                f16x8 a0 = wfrag(w01p, 16, ks, 4 * wv + 0, lane);
                f16x8 a1 = wfrag(w01p, 16, ks, 4 * wv + 1, lane);
                f16x8 a2f = wfrag(w01p, 16, ks, 4 * wv + 2, lane);
                f16x8 a3 = wfrag(w01p, 16, ks, 4 * wv + 3, lane);
                f16x8 b = afrag(lds, VB(j), 128, 0, ks * 32, lr, lg);
                a2[0] = MFMA16(a0, b, a2[0]);
                a2[1] = MFMA16(a1, b, a2[1]);
                a2[2] = MFMA16(a2f, b, a2[2]);
                a2[3] = MFMA16(a3, b, a2[3]);
            }
            #pragma unroll
            for (int c = 0; c < 4; ++c) {
                f16x4 t4;
                #pragma unroll
                for (int r = 0; r < 4; ++r)
                    t4[r] = (f16)(C011 * (float)s4r[c][r] * a2[c][r]);
                stsv4(lds, TB, 384, lr, wv * 64 + c * 16 + lg * 4, t4);
            }
        }
        #pragma unroll 1
        for (int q = tid; q < NT * 32; q += 256) {
            int row = q >> 5;
            int col = (q & 31) * 4;
            f16x4 v4 = ldsv4(lds, VB(j), 128, row, col);
            f16x4 a34 = ldsv4(lds, A3B, 128, row, col);
            f16x4 t4;
            #pragma unroll
            for (int r = 0; r < 4; ++r)
                t4[r] = (f16)(C101 * (float)v4[r] * (float)a34[r]);
            stsv4(lds, TB, 384, row, 256 + col, t4);
        }
        barrier_lds();
        {
            f16x8 a0 = wfrag(W1op, 8, 0, 2 * wv, lane);
            f16x8 a1 = wfrag(W1op, 8, 0, 2 * wv + 1, lane);
            #pragma unroll 1
            for (int ks = 0; ks < 12; ++ks) {
                int kn = ks + 1 < 12 ? ks + 1 : ks;
                f16x8 n0 = wfrag(W1op, 8, kn, 2 * wv, lane);
                f16x8 n1 = wfrag(W1op, 8, kn, 2 * wv + 1, lane);
                f16x8 b = afrag(lds, TB, 384, 0, ks * 32, lr, lg);
                acc1o[0][j] = MFMA16(a0, b, acc1o[0][j]);
                acc1o[1][j] = MFMA16(a1, b, acc1o[1][j]);
                a0 = n0; a1 = n1;
            }
        }
        barrier_lds();
    }
    #pragma unroll
    for (int r2 = 0; r2 < 2; ++r2) {
        if (lr < nvalid) {
            int o0 = (2 * wv + r2) * 16 + lg * 4;
            float vals[12];
            #pragma unroll
            for (int r = 0; r < 4; ++r)
                #pragma unroll
                for (int j = 0; j < 3; ++j)
                    vals[r * 3 + j] = RS384 * acc1o[r2][j][r];
            size_t base = (size_t)(z0 + lr) * 1024 + 256 + 3 * o0;
            #pragma unroll
            for (int qq = 0; qq < 3; ++qq) {
                float4 f;
                f.x = vals[qq * 4 + 0]; f.y = vals[qq * 4 + 1];
                f.z = vals[qq * 4 + 2]; f.w = vals[qq * 4 + 3];
                *(float4*)(&out[base + qq * 4]) = f;
            }
        }
    }

    // ---- P6: Mj^T = w111 @ Vj^T -> M planes; cross -> p5 planes ----
    #pragma unroll 1
    for (int j = 0; j < 3; ++j) {
        f32x4 am[2] = {};
        #pragma unroll
        for (int ks = 0; ks < 4; ++ks) {
            f16x8 a0 = wfrag(w111p, 8, ks, 2 * wv, lane);
            f16x8 a1 = wfrag(w111p, 8, ks, 2 * wv + 1, lane);
            f16x8 b = afrag(lds, VB(j), 128, 0, ks * 32, lr, lg);
            am[0] = MFMA16(a0, b, am[0]);
            am[1] = MFMA16(a1, b, am[1]);
        }
        #pragma unroll
        for (int r2 = 0; r2 < 2; ++r2) {
            f16x4 t4;
            #pragma unroll
            for (int r = 0; r < 4; ++r) t4[r] = (f16)am[r2][r];
            stsv4(lds, MBASE(j), 128, lr, (2 * wv + r2) * 16 + lg * 4, t4);
        }
    }
    barrier_lds();
    #pragma unroll 1
    for (int q = tid; q < NT * 32; q += 256) {
        int row = q >> 5;
        int col = (q & 31) * 4;
        f16x4 v0 = ldsv4(lds, VB(0), 128, row, col);
        f16x4 v1 = ldsv4(lds, VB(1), 128, row, col);
        f16x4 v2 = ldsv4(lds, VB(2), 128, row, col);
        f16x4 m0 = ldsv4(lds, MBASE(0), 128, row, col);
        f16x4 m1 = ldsv4(lds, MBASE(1), 128, row, col);
        f16x4 m2 = ldsv4(lds, MBASE(2), 128, row, col);
        f16x4 c0, c1, c2;
        #pragma unroll
        for (int r = 0; r < 4; ++r) {
            c0[r] = (f16)(C111 * ((float)v1[r] * (float)m2[r] - (float)v2[r] * (float)m1[r]));
            c1[r] = (f16)(C111 * ((float)v2[r] * (float)m0[r] - (float)v0[r] * (float)m2[r]));
            c2[r] = (f16)(C111 * ((float)v0[r] * (float)m1[r] - (float)v1[r] * (float)m0[r]));
        }
        stsv4(lds, P5BASE(0), 128, row, col, c0);
        stsv4(lds, P5BASE(1), 128, row, col, c1);
        stsv4(lds, P5BASE(2), 128, row, col, c2);
    }
    barrier_lds();

    // ---- P7: out_1e^T = W1e^T @ p5^T / sqrt(128) ----
    {
        f32x4 acc[2][3] = {};  // [r2][j]
        #pragma unroll
        for (int j = 0; j < 3; ++j)
            #pragma unroll
            for (int ks = 0; ks < 4; ++ks) {
                f16x8 a0 = wfrag(W1ep, 8, ks, 2 * wv, lane);
                f16x8 a1 = wfrag(W1ep, 8, ks, 2 * wv + 1, lane);
                f16x8 b = afrag(lds, P5BASE(j), 128, 0, ks * 32, lr, lg);
                acc[0][j] = MFMA16(a0, b, acc[0][j]);
                acc[1][j] = MFMA16(a1, b, acc[1][j]);
            }
        #pragma unroll
        for (int r2 = 0; r2 < 2; ++r2) {
            if (lr < nvalid) {
                int o0 = (2 * wv + r2) * 16 + lg * 4;
                float vals[12];
                #pragma unroll
                for (int r = 0; r < 4; ++r)
                    #pragma unroll
                    for (int j = 0; j < 3; ++j)
                        vals[r * 3 + j] = RS128 * acc[r2][j][r];
                size_t base = (size_t)(z0 + lr) * 1024 + 640 + 3 * o0;
                #pragma unroll
                for (int qq = 0; qq < 3; ++qq) {
                    float4 f;
                    f.x = vals[qq * 4 + 0]; f.y = vals[qq * 4 + 1];
                    f.z = vals[qq * 4 + 2]; f.w = vals[qq * 4 + 3];
                    *(float4*)(&out[base + qq * 4]) = f;
                }
            }
        }
    }
}

extern "C" void kernel_launch(void* const* d_in, const int* in_sizes, int n_in,
                              void* d_out, int out_size, void* d_ws, size_t ws_size,
                              hipStream_t stream) {
    const float* nf   = (const float*)d_in[0];
    const float* w00  = (const float*)d_in[1];
    const float* w01  = (const float*)d_in[2];
    const float* w10  = (const float*)d_in[3];
    const float* w110 = (const float*)d_in[4];
    const float* w111 = (const float*)d_in[5];
    const float* W0e  = (const float*)d_in[6];
    const float* W1o  = (const float*)d_in[7];
    const float* W1e  = (const float*)d_in[8];
    f16* wpack = (f16*)d_ws;  // needs 655,360 bytes

    int n_nodes = in_sizes[0] / 640;
    pack_weights<<<1280, 256, 0, stream>>>(w00, w01, w10, w110, w111, W0e, W1o, W1e, wpack);
    int blocks = (n_nodes + NT - 1) / NT;
    node_tp<<<blocks, 256, 0, stream>>>(nf, wpack, (float*)d_out, n_nodes);
}

// Round 11
// 198.582 us; speedup vs baseline: 1.3381x; 1.1847x over previous
//
#include <hip/hip_runtime.h>

typedef _Float16 f16;
typedef _Float16 f16x8 __attribute__((ext_vector_type(8)));
typedef _Float16 f16x4 __attribute__((ext_vector_type(4)));
typedef float f32x4 __attribute__((ext_vector_type(4)));

#define MFMA16(a, b, c) __builtin_amdgcn_mfma_f32_16x16x32_f16(a, b, c, 0, 0, 0)
#define PRIO_HI() __builtin_amdgcn_s_setprio(1)
#define PRIO_LO() __builtin_amdgcn_s_setprio(0)

// LDS-only barrier: drains LDS ops but leaves global loads/stores in flight.
// Legal: every barrier here protects only LDS data (weights read-only, out write-only).
__device__ __forceinline__ void barrier_lds() {
    asm volatile("s_waitcnt lgkmcnt(0)" ::: "memory");
    __builtin_amdgcn_s_barrier();
}

// ---------------- weight packing (A-operand layout) ----------------
// Panels over (kb, rb); each panel = 512 f16:
//   element ((kb*(R/16)+rb)*64 + lane)*8 + i  holds  A[r][k],
//   r = rb*16 + (lane&15),  k = kb*32 + (lane>>4)*8 + i
__device__ __forceinline__ void pack_one(int local, const float* __restrict__ src,
                                         f16* __restrict__ dst, int K, int R, int transpose) {
    int i = local & 7;
    int l = (local >> 3) & 63;
    int p = local >> 9;
    int rt16 = R >> 4;
    int rb = p % rt16;
    int kb = p / rt16;
    int k = kb * 32 + ((l >> 4) << 3) + i;
    int r = rb * 16 + (l & 15);
    float v = transpose ? src[k * R + r] : src[r * K + k];
    dst[local] = (f16)v;
}

__global__ void pack_weights(const float* __restrict__ w00, const float* __restrict__ w01,
                             const float* __restrict__ w10, const float* __restrict__ w110,
                             const float* __restrict__ w111, const float* __restrict__ W0e,
                             const float* __restrict__ W1o, const float* __restrict__ W1e,
                             f16* __restrict__ dst) {
    int idx = blockIdx.x * 256 + threadIdx.x;
    if (idx < 65536)        pack_one(idx,          w00,  dst,          256, 256, 0);
    else if (idx < 98304)   pack_one(idx - 65536,  w01,  dst + 65536,  128, 256, 0);
    else if (idx < 131072)  pack_one(idx - 98304,  w10,  dst + 98304,  256, 128, 0);
    else if (idx < 147456)  pack_one(idx - 131072, w110, dst + 131072, 128, 128, 0);
    else if (idx < 163840)  pack_one(idx - 147456, w111, dst + 147456, 128, 128, 0);
    else if (idx < 262144)  pack_one(idx - 163840, W0e,  dst + 163840, 384, 256, 1);
    else if (idx < 311296)  pack_one(idx - 262144, W1o,  dst + 262144, 384, 128, 1);
    else                    pack_one(idx - 311296, W1e,  dst + 311296, 128, 128, 1);
}

// ---------------- main fused kernel ----------------
// Best verified geometry (r5/r7): NT=32, 512 threads, 72K LDS -> 2 blocks/CU.
// lgkm-only barriers + cross-barrier weight preloads (r7) + s_setprio around
// MFMA clusters (T5: the 2 co-resident blocks sit at different phases; the
// MFMA-burst wave wins CU arbitration over the other block's staging waves).
#define NT 32
#define S16B   0                        // [32][256] f16, pitch 512B (16 KiB)
#define VBASE(j) (16384 + (j) * 8192)   // [32][128] f16, pitch 256B (3 x 8 KiB)
#define TB     40960                    // [32][384] f16, pitch 768B (24 KiB)
#define A3B    65536                    // [32][128] f16, pitch 256B (8 KiB)
#define MBASE(j) (TB + (j) * 8192)      // reuse T as three [32][128] planes
#define P5BASE(j) ((j) == 0 ? A3B : (S16B + ((j) - 1) * 8192))
#define LDS_BYTES 73728

__device__ __forceinline__ f16x8 afrag(const unsigned char* lds, int base, int pitchh,
                                       int row0, int k0, int lr, int lg) {
    int row = row0 + lr;
    int off = base + row * (pitchh * 2) + (((k0 + (lg << 3)) * 2) ^ ((row & 7) << 4));
    return *(const f16x8*)(lds + off);
}
__device__ __forceinline__ f16x4 ldsv4(const unsigned char* lds, int base, int pitchh,
                                       int row, int col) {
    int off = base + row * (pitchh * 2) + ((col * 2) ^ ((row & 7) << 4));
    return *(const f16x4*)(lds + off);
}
__device__ __forceinline__ void stsv4(unsigned char* lds, int base, int pitchh,
                                      int row, int col, f16x4 v) {
    int off = base + row * (pitchh * 2) + ((col * 2) ^ ((row & 7) << 4));
    *(f16x4*)(lds + off) = v;
}
__device__ __forceinline__ void ldss(unsigned char* lds, int base, int pitchh,
                                     int row, int col, float v) {
    int off = base + row * (pitchh * 2) + ((col * 2) ^ ((row & 7) << 4));
    *(f16*)(lds + off) = (f16)v;
}
__device__ __forceinline__ f16x8 wfrag(const f16* __restrict__ panel, int rt16, int kb,
                                       int rb, int lane) {
    return *(const f16x8*)(panel + (size_t)((kb * rt16 + rb) * 512 + lane * 8));
}

__global__ __launch_bounds__(512, 2)
void node_tp(const float* __restrict__ nf, const f16* __restrict__ wp,
             float* __restrict__ out, int n_nodes) {
    __shared__ __align__(16) unsigned char lds[LDS_BYTES];
    const int tid = threadIdx.x;
    const int lane = tid & 63;
    const int wv = tid >> 6;
    const int z0 = blockIdx.x * NT;
    const int nvalid = min(NT, n_nodes - z0);
    const int lr = lane & 15;
    const int lg = lane >> 4;
    const int ng = wv >> 2;   // node-tile (of 2) for split phases
    const int wr = wv & 3;    // channel-tile pair for split phases (128-wide)

    const f16* w00p  = wp;
    const f16* w01p  = wp + 65536;
    const f16* w10p  = wp + 98304;
    const f16* w110p = wp + 131072;
    const f16* w111p = wp + 147456;
    const f16* W0ep  = wp + 163840;
    const f16* W1op  = wp + 262144;
    const f16* W1ep  = wp + 311296;

    const float C000 = 0.0625f;               // 1/sqrt(256)
    const float C011 = 0.08838834764831843f;  // 1/sqrt(128)
    const float C101 = 0.0625f;
    const float C110 = 0.05103103630798287f;  // 1/sqrt(384)
    const float C111 = 0.0625f;               // 1/16
    const float RS384 = 0.05103103630798287f;
    const float RS128 = 0.08838834764831843f;

    // ---- P0: stage node_feat -> LDS f16 (swizzled, [node][channel]) ----
    #pragma unroll 5
    for (int q = tid; q < NT * 160; q += 512) {
        int row = q / 160;
        int c4 = q - row * 160;
        float4 v4 = make_float4(0.f, 0.f, 0.f, 0.f);
        if (row < nvalid)
            v4 = ((const float4*)(nf + (size_t)(z0 + row) * 640))[c4];
        int c = c4 * 4;
        if (c < 256) {
            f16x4 h = {(f16)v4.x, (f16)v4.y, (f16)v4.z, (f16)v4.w};
            int off = S16B + row * 512 + ((c * 2) ^ ((row & 7) << 4));
            *(f16x4*)(lds + off) = h;
        } else {
            float vv[4] = {v4.x, v4.y, v4.z, v4.w};
            #pragma unroll
            for (int e = 0; e < 4; ++e) {
                int m = c - 256 + e;
                int u = m / 3;
                int j = m - u * 3;
                ldss(lds, VBASE(j), 128, row, u, vv[e]);
            }
        }
    }
    // hoist P1's initial weight fragments above the barrier (fly during wait)
    f16x8 p1a0 = wfrag(w00p, 16, 0, 2 * wv, lane);
    f16x8 p1a1 = wfrag(w00p, 16, 0, 2 * wv + 1, lane);
    barrier_lds();

    // ---- P1: A1^T = w00 @ S^T ; p1 = C000*S*A1 -> T[:,0:256] (full-nt) ----
    {
        f32x4 acc[2][2] = {};
        f16x8 a0 = p1a0, a1 = p1a1;
        #pragma unroll 1
        for (int ks = 0; ks < 8; ++ks) {
            int kn = ks + 1 < 8 ? ks + 1 : ks;
            f16x8 n0 = wfrag(w00p, 16, kn, 2 * wv, lane);
            f16x8 n1 = wfrag(w00p, 16, kn, 2 * wv + 1, lane);
            PRIO_HI();
            #pragma unroll
            for (int nt = 0; nt < 2; ++nt) {
                f16x8 b = afrag(lds, S16B, 256, nt * 16, ks * 32, lr, lg);
                acc[0][nt] = MFMA16(a0, b, acc[0][nt]);
                acc[1][nt] = MFMA16(a1, b, acc[1][nt]);
            }
            PRIO_LO();
            a0 = n0; a1 = n1;
        }
        #pragma unroll
        for (int rt = 0; rt < 2; ++rt)
            #pragma unroll
            for (int nt = 0; nt < 2; ++nt) {
                int node = nt * 16 + lr;
                int u0 = wv * 32 + rt * 16 + lg * 4;
                f16x4 s4 = ldsv4(lds, S16B, 256, node, u0);
                f16x4 t4;
                #pragma unroll
                for (int r = 0; r < 4; ++r)
                    t4[r] = (f16)(C000 * (float)s4[r] * acc[rt][nt][r]);
                stsv4(lds, TB, 384, node, u0, t4);
            }
    }
    // ---- P2: A4j^T = w110 @ Vj^T ; p4 = C110*sum_j Vj*A4j -> T[:,256:384] (split) ----
    {
        f32x4 acc[3][2] = {};  // [j][r2]
        PRIO_HI();
        #pragma unroll
        for (int ks = 0; ks < 4; ++ks) {
            f16x8 a0 = wfrag(w110p, 8, ks, 2 * wr, lane);
            f16x8 a1 = wfrag(w110p, 8, ks, 2 * wr + 1, lane);
            #pragma unroll
            for (int j = 0; j < 3; ++j) {
                f16x8 b = afrag(lds, VBASE(j), 128, ng * 16, ks * 32, lr, lg);
                acc[j][0] = MFMA16(a0, b, acc[j][0]);
                acc[j][1] = MFMA16(a1, b, acc[j][1]);
            }
        }
        PRIO_LO();
        #pragma unroll
        for (int r2 = 0; r2 < 2; ++r2) {
            int node = ng * 16 + lr;
            int u0 = (2 * wr + r2) * 16 + lg * 4;
            float p4[4] = {0.f, 0.f, 0.f, 0.f};
            #pragma unroll
            for (int j = 0; j < 3; ++j) {
                f16x4 v4 = ldsv4(lds, VBASE(j), 128, node, u0);
                #pragma unroll
                for (int r = 0; r < 4; ++r)
                    p4[r] += (float)v4[r] * acc[j][r2][r];
            }
            f16x4 t4;
            #pragma unroll
            for (int r = 0; r < 4; ++r) t4[r] = (f16)(C110 * p4[r]);
            stsv4(lds, TB, 384, node, 256 + u0, t4);
        }
    }
    // hoist P3's initial W0e fragments above the barrier
    f16x8 p3a0 = wfrag(W0ep, 16, 0, 2 * wv, lane);
    f16x8 p3a1 = wfrag(W0ep, 16, 0, 2 * wv + 1, lane);
    barrier_lds();

    // ---- P3: out_0e^T = W0e^T @ T^T / sqrt(384) (full-nt) ----
    {
        f32x4 acc[2][2] = {};
        f16x8 a0 = p3a0, a1 = p3a1;
        #pragma unroll 1
        for (int ks = 0; ks < 12; ++ks) {
            int kn = ks + 1 < 12 ? ks + 1 : ks;
            f16x8 n0 = wfrag(W0ep, 16, kn, 2 * wv, lane);
            f16x8 n1 = wfrag(W0ep, 16, kn, 2 * wv + 1, lane);
            PRIO_HI();
            #pragma unroll
            for (int nt = 0; nt < 2; ++nt) {
                f16x8 b = afrag(lds, TB, 384, nt * 16, ks * 32, lr, lg);
                acc[0][nt] = MFMA16(a0, b, acc[0][nt]);
                acc[1][nt] = MFMA16(a1, b, acc[1][nt]);
            }
            PRIO_LO();
            a0 = n0; a1 = n1;
        }
        #pragma unroll
        for (int rt = 0; rt < 2; ++rt)
            #pragma unroll
            for (int nt = 0; nt < 2; ++nt) {
                int node = nt * 16 + lr;
                if (node < nvalid) {
                    int o = wv * 32 + rt * 16 + lg * 4;
                    float4 o4;
                    o4.x = RS384 * acc[rt][nt][0];
                    o4.y = RS384 * acc[rt][nt][1];
                    o4.z = RS384 * acc[rt][nt][2];
                    o4.w = RS384 * acc[rt][nt][3];
                    *(float4*)(&out[(size_t)(z0 + node) * 1024 + o]) = o4;
                }
            }
    }
    // ---- P4: A3^T = w10 @ S^T -> A3B (split) ----
    {
        f32x4 acc[2] = {};
        f16x8 a0 = wfrag(w10p, 8, 0, 2 * wr, lane);
        f16x8 a1 = wfrag(w10p, 8, 0, 2 * wr + 1, lane);
        #pragma unroll 1
        for (int ks = 0; ks < 8; ++ks) {
            int kn = ks + 1 < 8 ? ks + 1 : ks;
            f16x8 n0 = wfrag(w10p, 8, kn, 2 * wr, lane);
            f16x8 n1 = wfrag(w10p, 8, kn, 2 * wr + 1, lane);
            PRIO_HI();
            f16x8 b = afrag(lds, S16B, 256, ng * 16, ks * 32, lr, lg);
            acc[0] = MFMA16(a0, b, acc[0]);
            acc[1] = MFMA16(a1, b, acc[1]);
            PRIO_LO();
            a0 = n0; a1 = n1;
        }
        #pragma unroll
        for (int r2 = 0; r2 < 2; ++r2) {
            int node = ng * 16 + lr;
            f16x4 t4;
            #pragma unroll
            for (int r = 0; r < 4; ++r) t4[r] = (f16)acc[r2][r];
            stsv4(lds, A3B, 128, node, (2 * wr + r2) * 16 + lg * 4, t4);
        }
    }
    barrier_lds();

    // ---- P5: for j: {A2j -> p2 -> T[:,0:256]; p3 -> T[:,256:384]; out1o += W1o^T@T^T} ----
    f32x4 acc1o[2][3] = {};  // [r2][j]
    #pragma unroll
    for (int j = 0; j < 3; ++j) {
        {
            f32x4 a2[2][2] = {};
            PRIO_HI();
            #pragma unroll
            for (int ks = 0; ks < 4; ++ks) {
                f16x8 a0 = wfrag(w01p, 16, ks, 2 * wv, lane);
                f16x8 a1 = wfrag(w01p, 16, ks, 2 * wv + 1, lane);
                #pragma unroll
                for (int nt = 0; nt < 2; ++nt) {
                    f16x8 b = afrag(lds, VBASE(j), 128, nt * 16, ks * 32, lr, lg);
                    a2[0][nt] = MFMA16(a0, b, a2[0][nt]);
                    a2[1][nt] = MFMA16(a1, b, a2[1][nt]);
                }
            }
            PRIO_LO();
            #pragma unroll
            for (int rt = 0; rt < 2; ++rt)
                #pragma unroll
                for (int nt = 0; nt < 2; ++nt) {
                    int node = nt * 16 + lr;
                    int u0 = wv * 32 + rt * 16 + lg * 4;
                    f16x4 s4 = ldsv4(lds, S16B, 256, node, u0);
                    f16x4 t4;
                    #pragma unroll
                    for (int r = 0; r < 4; ++r)
                        t4[r] = (f16)(C011 * (float)s4[r] * a2[rt][nt][r]);
                    stsv4(lds, TB, 384, node, u0, t4);
                }
        }
        #pragma unroll 1
        for (int q = tid; q < NT * 32; q += 512) {
            int z = q >> 5;
            int col = (q & 31) * 4;
            f16x4 v4 = ldsv4(lds, VBASE(j), 128, z, col);
            f16x4 a34 = ldsv4(lds, A3B, 128, z, col);
            f16x4 t4;
            #pragma unroll
            for (int r = 0; r < 4; ++r)
                t4[r] = (f16)(C101 * (float)v4[r] * (float)a34[r]);
            stsv4(lds, TB, 384, z, 256 + col, t4);
        }
        // hoist W1o's initial fragments above the mid-j barrier
        f16x8 w1a0 = wfrag(W1op, 8, 0, 2 * wr, lane);
        f16x8 w1a1 = wfrag(W1op, 8, 0, 2 * wr + 1, lane);
        barrier_lds();
        {
            f16x8 a0 = w1a0, a1 = w1a1;
            #pragma unroll 1
            for (int ks = 0; ks < 12; ++ks) {
                int kn = ks + 1 < 12 ? ks + 1 : ks;
                f16x8 n0 = wfrag(W1op, 8, kn, 2 * wr, lane);
                f16x8 n1 = wfrag(W1op, 8, kn, 2 * wr + 1, lane);
                PRIO_HI();
                f16x8 b = afrag(lds, TB, 384, ng * 16, ks * 32, lr, lg);
                acc1o[0][j] = MFMA16(a0, b, acc1o[0][j]);
                acc1o[1][j] = MFMA16(a1, b, acc1o[1][j]);
                PRIO_LO();
                a0 = n0; a1 = n1;
            }
        }
        barrier_lds();
    }
    #pragma unroll
    for (int r2 = 0; r2 < 2; ++r2) {
        int node = ng * 16 + lr;
        if (node < nvalid) {
            int o0 = (2 * wr + r2) * 16 + lg * 4;
            float vals[12];
            #pragma unroll
            for (int r = 0; r < 4; ++r)
                #pragma unroll
                for (int j = 0; j < 3; ++j)
                    vals[r * 3 + j] = RS384 * acc1o[r2][j][r];
            size_t base = (size_t)(z0 + node) * 1024 + 256 + 3 * o0;
            #pragma unroll
            for (int qq = 0; qq < 3; ++qq) {
                float4 f;
                f.x = vals[qq * 4 + 0]; f.y = vals[qq * 4 + 1];
                f.z = vals[qq * 4 + 2]; f.w = vals[qq * 4 + 3];
                *(float4*)(&out[base + qq * 4]) = f;
            }
        }
    }

    // ---- P6: Mj^T = w111 @ Vj^T -> M planes (split); cross -> p5 planes ----
    #pragma unroll 1
    for (int j = 0; j < 3; ++j) {
        f32x4 am[2] = {};
        PRIO_HI();
        #pragma unroll
        for (int ks = 0; ks < 4; ++ks) {
            f16x8 a0 = wfrag(w111p, 8, ks, 2 * wr, lane);
            f16x8 a1 = wfrag(w111p, 8, ks, 2 * wr + 1, lane);
            f16x8 b = afrag(lds, VBASE(j), 128, ng * 16, ks * 32, lr, lg);
            am[0] = MFMA16(a0, b, am[0]);
            am[1] = MFMA16(a1, b, am[1]);
        }
        PRIO_LO();
        #pragma unroll
        for (int r2 = 0; r2 < 2; ++r2) {
            int node = ng * 16 + lr;
            f16x4 t4;
            #pragma unroll
            for (int r = 0; r < 4; ++r) t4[r] = (f16)am[r2][r];
            stsv4(lds, MBASE(j), 128, node, (2 * wr + r2) * 16 + lg * 4, t4);
        }
    }
    barrier_lds();
    #pragma unroll 1
    for (int q = tid; q < NT * 32; q += 512) {
        int z = q >> 5;
        int col = (q & 31) * 4;
        f16x4 v0 = ldsv4(lds, VBASE(0), 128, z, col);
        f16x4 v1 = ldsv4(lds, VBASE(1), 128, z, col);
        f16x4 v2 = ldsv4(lds, VBASE(2), 128, z, col);
        f16x4 m0 = ldsv4(lds, MBASE(0), 128, z, col);
        f16x4 m1 = ldsv4(lds, MBASE(1), 128, z, col);
        f16x4 m2 = ldsv4(lds, MBASE(2), 128, z, col);
        f16x4 c0, c1, c2;
        #pragma unroll
        for (int r = 0; r < 4; ++r) {
            c0[r] = (f16)(C111 * ((float)v1[r] * (float)m2[r] - (float)v2[r] * (float)m1[r]));
            c1[r] = (f16)(C111 * ((float)v2[r] * (float)m0[r] - (float)v0[r] * (float)m2[r]));
            c2[r] = (f16)(C111 * ((float)v0[r] * (float)m1[r] - (float)v1[r] * (float)m0[r]));
        }
        stsv4(lds, P5BASE(0), 128, z, col, c0);
        stsv4(lds, P5BASE(1), 128, z, col, c1);
        stsv4(lds, P5BASE(2), 128, z, col, c2);
    }
    // hoist P7's first W1e fragments above the barrier
    f16x8 p7a0 = wfrag(W1ep, 8, 0, 2 * wr, lane);
    f16x8 p7a1 = wfrag(W1ep, 8, 0, 2 * wr + 1, lane);
    barrier_lds();

    // ---- P7: out_1e^T = W1e^T @ p5^T / sqrt(128) (split) ----
    {
        f32x4 acc[2][3] = {};  // [r2][j]
        PRIO_HI();
        #pragma unroll
        for (int j = 0; j < 3; ++j)
            #pragma unroll
            for (int ks = 0; ks < 4; ++ks) {
                f16x8 a0 = (j == 0 && ks == 0) ? p7a0 : wfrag(W1ep, 8, ks, 2 * wr, lane);
                f16x8 a1 = (j == 0 && ks == 0) ? p7a1 : wfrag(W1ep, 8, ks, 2 * wr + 1, lane);
                f16x8 b = afrag(lds, P5BASE(j), 128, ng * 16, ks * 32, lr, lg);
                acc[0][j] = MFMA16(a0, b, acc[0][j]);
                acc[1][j] = MFMA16(a1, b, acc[1][j]);
            }
        PRIO_LO();
        #pragma unroll
        for (int r2 = 0; r2 < 2; ++r2) {
            int node = ng * 16 + lr;
            if (node < nvalid) {
                int o0 = (2 * wr + r2) * 16 + lg * 4;
                float vals[12];
                #pragma unroll
                for (int r = 0; r < 4; ++r)
                    #pragma unroll
                    for (int j = 0; j < 3; ++j)
                        vals[r * 3 + j] = RS128 * acc[r2][j][r];
                size_t base = (size_t)(z0 + node) * 1024 + 640 + 3 * o0;
                #pragma unroll
                for (int qq = 0; qq < 3; ++qq) {
                    float4 f;
                    f.x = vals[qq * 4 + 0]; f.y = vals[qq * 4 + 1];
                    f.z = vals[qq * 4 + 2]; f.w = vals[qq * 4 + 3];
                    *(float4*)(&out[base + qq * 4]) = f;
                }
            }
        }
    }
}

extern "C" void kernel_launch(void* const* d_in, const int* in_sizes, int n_in,
                              void* d_out, int out_size, void* d_ws, size_t ws_size,
                              hipStream_t stream) {
    const float* nf   = (const float*)d_in[0];
    const float* w00  = (const float*)d_in[1];
    const float* w01  = (const float*)d_in[2];
    const float* w10  = (const float*)d_in[3];
    const float* w110 = (const float*)d_in[4];
    const float* w111 = (const float*)d_in[5];
    const float* W0e  = (const float*)d_in[6];
    const float* W1o  = (const float*)d_in[7];
    const float* W1e  = (const float*)d_in[8];
    f16* wpack = (f16*)d_ws;  // needs 655,360 bytes

    int n_nodes = in_sizes[0] / 640;
    pack_weights<<<1280, 256, 0, stream>>>(w00, w01, w10, w110, w111, W0e, W1o, W1e, wpack);
    int blocks = (n_nodes + NT - 1) / NT;
    node_tp<<<blocks, 512, 0, stream>>>(nf, wpack, (float*)d_out, n_nodes);
}

// Round 12
// 195.538 us; speedup vs baseline: 1.3589x; 1.0156x over previous
//
#include <hip/hip_runtime.h>

typedef _Float16 f16;
typedef _Float16 f16x8 __attribute__((ext_vector_type(8)));
typedef _Float16 f16x4 __attribute__((ext_vector_type(4)));
typedef float f32x4 __attribute__((ext_vector_type(4)));

#define MFMA16(a, b, c) __builtin_amdgcn_mfma_f32_16x16x32_f16(a, b, c, 0, 0, 0)

// LDS-only barrier: drains LDS ops (lgkmcnt) but leaves global loads/stores
// (vmcnt) in flight across the barrier. Legal here because every barrier in
// this kernel protects only LDS data: weights are read-only global, `out` is
// write-only.
__device__ __forceinline__ void barrier_lds() {
    asm volatile("s_waitcnt lgkmcnt(0)" ::: "memory");
    __builtin_amdgcn_s_barrier();
}

// ---------------- weight packing (A-operand layout) ----------------
// Panels over (kb, rb); each panel = 512 f16:
//   element ((kb*(R/16)+rb)*64 + lane)*8 + i  holds  A[r][k],
//   r = rb*16 + (lane&15),  k = kb*32 + (lane>>4)*8 + i
//   A[r][k] = transpose ? W[k*R+r] : W[r*K+k]
__device__ __forceinline__ void pack_one(int local, const float* __restrict__ src,
                                         f16* __restrict__ dst, int K, int R, int transpose) {
    int i = local & 7;
    int l = (local >> 3) & 63;
    int p = local >> 9;
    int rt16 = R >> 4;
    int rb = p % rt16;
    int kb = p / rt16;
    int k = kb * 32 + ((l >> 4) << 3) + i;
    int r = rb * 16 + (l & 15);
    float v = transpose ? src[k * R + r] : src[r * K + k];
    dst[local] = (f16)v;
}

__global__ void pack_weights(const float* __restrict__ w00, const float* __restrict__ w01,
                             const float* __restrict__ w10, const float* __restrict__ w110,
                             const float* __restrict__ w111, const float* __restrict__ W0e,
                             const float* __restrict__ W1o, const float* __restrict__ W1e,
                             f16* __restrict__ dst) {
    int idx = blockIdx.x * 256 + threadIdx.x;
    if (idx < 65536)        pack_one(idx,          w00,  dst,          256, 256, 0);
    else if (idx < 98304)   pack_one(idx - 65536,  w01,  dst + 65536,  128, 256, 0);
    else if (idx < 131072)  pack_one(idx - 98304,  w10,  dst + 98304,  256, 128, 0);
    else if (idx < 147456)  pack_one(idx - 131072, w110, dst + 131072, 128, 128, 0);
    else if (idx < 163840)  pack_one(idx - 147456, w111, dst + 147456, 128, 128, 0);
    else if (idx < 262144)  pack_one(idx - 163840, W0e,  dst + 163840, 384, 256, 1);
    else if (idx < 311296)  pack_one(idx - 262144, W1o,  dst + 262144, 384, 128, 1);
    else                    pack_one(idx - 311296, W1e,  dst + 311296, 128, 128, 1);
}

// ---------------- main fused kernel ----------------
// Session optimum (r7): NT=32, 512 threads, 72K LDS -> 2 blocks/CU,
// transposed orientation (C[channel][node], weights = A-operand),
// lgkm-only barriers + cross-barrier weight-preload hoisting.
#define NT 32
#define S16B   0                        // [32][256] f16, pitch 512B (16 KiB)
#define VBASE(j) (16384 + (j) * 8192)   // [32][128] f16, pitch 256B (3 x 8 KiB)
#define TB     40960                    // [32][384] f16, pitch 768B (24 KiB)
#define A3B    65536                    // [32][128] f16, pitch 256B (8 KiB)
#define MBASE(j) (TB + (j) * 8192)      // reuse T as three [32][128] planes
#define P5BASE(j) ((j) == 0 ? A3B : (S16B + ((j) - 1) * 8192))
#define LDS_BYTES 73728

__device__ __forceinline__ f16x8 afrag(const unsigned char* lds, int base, int pitchh,
                                       int row0, int k0, int lr, int lg) {
    int row = row0 + lr;
    int off = base + row * (pitchh * 2) + (((k0 + (lg << 3)) * 2) ^ ((row & 7) << 4));
    return *(const f16x8*)(lds + off);
}
__device__ __forceinline__ f16x4 ldsv4(const unsigned char* lds, int base, int pitchh,
                                       int row, int col) {
    int off = base + row * (pitchh * 2) + ((col * 2) ^ ((row & 7) << 4));
    return *(const f16x4*)(lds + off);
}
__device__ __forceinline__ void stsv4(unsigned char* lds, int base, int pitchh,
                                      int row, int col, f16x4 v) {
    int off = base + row * (pitchh * 2) + ((col * 2) ^ ((row & 7) << 4));
    *(f16x4*)(lds + off) = v;
}
__device__ __forceinline__ void ldss(unsigned char* lds, int base, int pitchh,
                                     int row, int col, float v) {
    int off = base + row * (pitchh * 2) + ((col * 2) ^ ((row & 7) << 4));
    *(f16*)(lds + off) = (f16)v;
}
__device__ __forceinline__ f16x8 wfrag(const f16* __restrict__ panel, int rt16, int kb,
                                       int rb, int lane) {
    return *(const f16x8*)(panel + (size_t)((kb * rt16 + rb) * 512 + lane * 8));
}

__global__ __launch_bounds__(512, 2)
void node_tp(const float* __restrict__ nf, const f16* __restrict__ wp,
             float* __restrict__ out, int n_nodes) {
    __shared__ __align__(16) unsigned char lds[LDS_BYTES];
    const int tid = threadIdx.x;
    const int lane = tid & 63;
    const int wv = tid >> 6;
    const int z0 = blockIdx.x * NT;
    const int nvalid = min(NT, n_nodes - z0);
    const int lr = lane & 15;
    const int lg = lane >> 4;
    const int ng = wv >> 2;   // node-tile (of 2) for split phases
    const int wr = wv & 3;    // channel-tile pair for split phases (128-wide)

    const f16* w00p  = wp;
    const f16* w01p  = wp + 65536;
    const f16* w10p  = wp + 98304;
    const f16* w110p = wp + 131072;
    const f16* w111p = wp + 147456;
    const f16* W0ep  = wp + 163840;
    const f16* W1op  = wp + 262144;
    const f16* W1ep  = wp + 311296;

    const float C000 = 0.0625f;               // 1/sqrt(256)
    const float C011 = 0.08838834764831843f;  // 1/sqrt(128)
    const float C101 = 0.0625f;
    const float C110 = 0.05103103630798287f;  // 1/sqrt(384)
    const float C111 = 0.0625f;               // 1/16
    const float RS384 = 0.05103103630798287f;
    const float RS128 = 0.08838834764831843f;

    // ---- P0: stage node_feat -> LDS f16 (swizzled, [node][channel]) ----
    #pragma unroll 5
    for (int q = tid; q < NT * 160; q += 512) {
        int row = q / 160;
        int c4 = q - row * 160;
        float4 v4 = make_float4(0.f, 0.f, 0.f, 0.f);
        if (row < nvalid)
            v4 = ((const float4*)(nf + (size_t)(z0 + row) * 640))[c4];
        int c = c4 * 4;
        if (c < 256) {
            f16x4 h = {(f16)v4.x, (f16)v4.y, (f16)v4.z, (f16)v4.w};
            int off = S16B + row * 512 + ((c * 2) ^ ((row & 7) << 4));
            *(f16x4*)(lds + off) = h;
        } else {
            float vv[4] = {v4.x, v4.y, v4.z, v4.w};
            #pragma unroll
            for (int e = 0; e < 4; ++e) {
                int m = c - 256 + e;
                int u = m / 3;
                int j = m - u * 3;
                ldss(lds, VBASE(j), 128, row, u, vv[e]);
            }
        }
    }
    // hoist P1's initial weight fragments above the barrier (fly during wait)
    f16x8 p1a0 = wfrag(w00p, 16, 0, 2 * wv, lane);
    f16x8 p1a1 = wfrag(w00p, 16, 0, 2 * wv + 1, lane);
    barrier_lds();

    // ---- P1: A1^T = w00 @ S^T ; p1 = C000*S*A1 -> T[:,0:256] (full-nt) ----
    {
        f32x4 acc[2][2] = {};
        f16x8 a0 = p1a0, a1 = p1a1;
        #pragma unroll 1
        for (int ks = 0; ks < 8; ++ks) {
            int kn = ks + 1 < 8 ? ks + 1 : ks;
            f16x8 n0 = wfrag(w00p, 16, kn, 2 * wv, lane);
            f16x8 n1 = wfrag(w00p, 16, kn, 2 * wv + 1, lane);
            #pragma unroll
            for (int nt = 0; nt < 2; ++nt) {
                f16x8 b = afrag(lds, S16B, 256, nt * 16, ks * 32, lr, lg);
                acc[0][nt] = MFMA16(a0, b, acc[0][nt]);
                acc[1][nt] = MFMA16(a1, b, acc[1][nt]);
            }
            a0 = n0; a1 = n1;
        }
        #pragma unroll
        for (int rt = 0; rt < 2; ++rt)
            #pragma unroll
            for (int nt = 0; nt < 2; ++nt) {
                int node = nt * 16 + lr;
                int u0 = wv * 32 + rt * 16 + lg * 4;
                f16x4 s4 = ldsv4(lds, S16B, 256, node, u0);
                f16x4 t4;
                #pragma unroll
                for (int r = 0; r < 4; ++r)
                    t4[r] = (f16)(C000 * (float)s4[r] * acc[rt][nt][r]);
                stsv4(lds, TB, 384, node, u0, t4);
            }
    }
    // ---- P2: A4j^T = w110 @ Vj^T ; p4 = C110*sum_j Vj*A4j -> T[:,256:384] (split) ----
    {
        f32x4 acc[3][2] = {};  // [j][r2]
        #pragma unroll
        for (int ks = 0; ks < 4; ++ks) {
            f16x8 a0 = wfrag(w110p, 8, ks, 2 * wr, lane);
            f16x8 a1 = wfrag(w110p, 8, ks, 2 * wr + 1, lane);
            #pragma unroll
            for (int j = 0; j < 3; ++j) {
                f16x8 b = afrag(lds, VBASE(j), 128, ng * 16, ks * 32, lr, lg);
                acc[j][0] = MFMA16(a0, b, acc[j][0]);
                acc[j][1] = MFMA16(a1, b, acc[j][1]);
            }
        }
        #pragma unroll
        for (int r2 = 0; r2 < 2; ++r2) {
            int node = ng * 16 + lr;
            int u0 = (2 * wr + r2) * 16 + lg * 4;
            float p4[4] = {0.f, 0.f, 0.f, 0.f};
            #pragma unroll
            for (int j = 0; j < 3; ++j) {
                f16x4 v4 = ldsv4(lds, VBASE(j), 128, node, u0);
                #pragma unroll
                for (int r = 0; r < 4; ++r)
                    p4[r] += (float)v4[r] * acc[j][r2][r];
            }
            f16x4 t4;
            #pragma unroll
            for (int r = 0; r < 4; ++r) t4[r] = (f16)(C110 * p4[r]);
            stsv4(lds, TB, 384, node, 256 + u0, t4);
        }
    }
    // hoist P3's initial W0e fragments above the barrier
    f16x8 p3a0 = wfrag(W0ep, 16, 0, 2 * wv, lane);
    f16x8 p3a1 = wfrag(W0ep, 16, 0, 2 * wv + 1, lane);
    barrier_lds();

    // ---- P3: out_0e^T = W0e^T @ T^T / sqrt(384) (full-nt) ----
    {
        f32x4 acc[2][2] = {};
        f16x8 a0 = p3a0, a1 = p3a1;
        #pragma unroll 1
        for (int ks = 0; ks < 12; ++ks) {
            int kn = ks + 1 < 12 ? ks + 1 : ks;
            f16x8 n0 = wfrag(W0ep, 16, kn, 2 * wv, lane);
            f16x8 n1 = wfrag(W0ep, 16, kn, 2 * wv + 1, lane);
            #pragma unroll
            for (int nt = 0; nt < 2; ++nt) {
                f16x8 b = afrag(lds, TB, 384, nt * 16, ks * 32, lr, lg);
                acc[0][nt] = MFMA16(a0, b, acc[0][nt]);
                acc[1][nt] = MFMA16(a1, b, acc[1][nt]);
            }
            a0 = n0; a1 = n1;
        }
        #pragma unroll
        for (int rt = 0; rt < 2; ++rt)
            #pragma unroll
            for (int nt = 0; nt < 2; ++nt) {
                int node = nt * 16 + lr;
                if (node < nvalid) {
                    int o = wv * 32 + rt * 16 + lg * 4;
                    float4 o4;
                    o4.x = RS384 * acc[rt][nt][0];
                    o4.y = RS384 * acc[rt][nt][1];
                    o4.z = RS384 * acc[rt][nt][2];
                    o4.w = RS384 * acc[rt][nt][3];
                    *(float4*)(&out[(size_t)(z0 + node) * 1024 + o]) = o4;
                }
            }
    }
    // ---- P4: A3^T = w10 @ S^T -> A3B (split) ----
    {
        f32x4 acc[2] = {};
        f16x8 a0 = wfrag(w10p, 8, 0, 2 * wr, lane);
        f16x8 a1 = wfrag(w10p, 8, 0, 2 * wr + 1, lane);
        #pragma unroll 1
        for (int ks = 0; ks < 8; ++ks) {
            int kn = ks + 1 < 8 ? ks + 1 : ks;
            f16x8 n0 = wfrag(w10p, 8, kn, 2 * wr, lane);
            f16x8 n1 = wfrag(w10p, 8, kn, 2 * wr + 1, lane);
            f16x8 b = afrag(lds, S16B, 256, ng * 16, ks * 32, lr, lg);
            acc[0] = MFMA16(a0, b, acc[0]);
            acc[1] = MFMA16(a1, b, acc[1]);
            a0 = n0; a1 = n1;
        }
        #pragma unroll
        for (int r2 = 0; r2 < 2; ++r2) {
            int node = ng * 16 + lr;
            f16x4 t4;
            #pragma unroll
            for (int r = 0; r < 4; ++r) t4[r] = (f16)acc[r2][r];
            stsv4(lds, A3B, 128, node, (2 * wr + r2) * 16 + lg * 4, t4);
        }
    }
    barrier_lds();

    // ---- P5: for j: {A2j -> p2 -> T[:,0:256]; p3 -> T[:,256:384]; out1o += W1o^T@T^T} ----
    f32x4 acc1o[2][3] = {};  // [r2][j]
    #pragma unroll
    for (int j = 0; j < 3; ++j) {
        {
            f32x4 a2[2][2] = {};
            #pragma unroll
            for (int ks = 0; ks < 4; ++ks) {
                f16x8 a0 = wfrag(w01p, 16, ks, 2 * wv, lane);
                f16x8 a1 = wfrag(w01p, 16, ks, 2 * wv + 1, lane);
                #pragma unroll
                for (int nt = 0; nt < 2; ++nt) {
                    f16x8 b = afrag(lds, VBASE(j), 128, nt * 16, ks * 32, lr, lg);
                    a2[0][nt] = MFMA16(a0, b, a2[0][nt]);
                    a2[1][nt] = MFMA16(a1, b, a2[1][nt]);
                }
            }
            #pragma unroll
            for (int rt = 0; rt < 2; ++rt)
                #pragma unroll
                for (int nt = 0; nt < 2; ++nt) {
                    int node = nt * 16 + lr;
                    int u0 = wv * 32 + rt * 16 + lg * 4;
                    f16x4 s4 = ldsv4(lds, S16B, 256, node, u0);
                    f16x4 t4;
                    #pragma unroll
                    for (int r = 0; r < 4; ++r)
                        t4[r] = (f16)(C011 * (float)s4[r] * a2[rt][nt][r]);
                    stsv4(lds, TB, 384, node, u0, t4);
                }
        }
        #pragma unroll 1
        for (int q = tid; q < NT * 32; q += 512) {
            int row = q >> 5;
            int col = (q & 31) * 4;
            f16x4 v4 = ldsv4(lds, VBASE(j), 128, row, col);
            f16x4 a34 = ldsv4(lds, A3B, 128, row, col);
            f16x4 t4;
            #pragma unroll
            for (int r = 0; r < 4; ++r)
                t4[r] = (f16)(C101 * (float)v4[r] * (float)a34[r]);
            stsv4(lds, TB, 384, row, 256 + col, t4);
        }
        // hoist W1o's initial fragments above the mid-j barrier
        f16x8 w1a0 = wfrag(W1op, 8, 0, 2 * wr, lane);
        f16x8 w1a1 = wfrag(W1op, 8, 0, 2 * wr + 1, lane);
        barrier_lds();
        {
            f16x8 a0 = w1a0, a1 = w1a1;
            #pragma unroll 1
            for (int ks = 0; ks < 12; ++ks) {
                int kn = ks + 1 < 12 ? ks + 1 : ks;
                f16x8 n0 = wfrag(W1op, 8, kn, 2 * wr, lane);
                f16x8 n1 = wfrag(W1op, 8, kn, 2 * wr + 1, lane);
                f16x8 b = afrag(lds, TB, 384, ng * 16, ks * 32, lr, lg);
                acc1o[0][j] = MFMA16(a0, b, acc1o[0][j]);
                acc1o[1][j] = MFMA16(a1, b, acc1o[1][j]);
                a0 = n0; a1 = n1;
            }
        }
        barrier_lds();
    }
    #pragma unroll
    for (int r2 = 0; r2 < 2; ++r2) {
        int node = ng * 16 + lr;
        if (node < nvalid) {
            int o0 = (2 * wr + r2) * 16 + lg * 4;
            float vals[12];
            #pragma unroll
            for (int r = 0; r < 4; ++r)
                #pragma unroll
                for (int j = 0; j < 3; ++j)
                    vals[r * 3 + j] = RS384 * acc1o[r2][j][r];
            size_t base = (size_t)(z0 + node) * 1024 + 256 + 3 * o0;
            #pragma unroll
            for (int qq = 0; qq < 3; ++qq) {
                float4 f;
                f.x = vals[qq * 4 + 0]; f.y = vals[qq * 4 + 1];
                f.z = vals[qq * 4 + 2]; f.w = vals[qq * 4 + 3];
                *(float4*)(&out[base + qq * 4]) = f;
            }
        }
    }

    // ---- P6: Mj^T = w111 @ Vj^T -> M planes (split); cross -> p5 planes ----
    #pragma unroll 1
    for (int j = 0; j < 3; ++j) {
        f32x4 am[2] = {};
        #pragma unroll
        for (int ks = 0; ks < 4; ++ks) {
            f16x8 a0 = wfrag(w111p, 8, ks, 2 * wr, lane);
            f16x8 a1 = wfrag(w111p, 8, ks, 2 * wr + 1, lane);
            f16x8 b = afrag(lds, VBASE(j), 128, ng * 16, ks * 32, lr, lg);
            am[0] = MFMA16(a0, b, am[0]);
            am[1] = MFMA16(a1, b, am[1]);
        }
        #pragma unroll
        for (int r2 = 0; r2 < 2; ++r2) {
            int node = ng * 16 + lr;
            f16x4 t4;
            #pragma unroll
            for (int r = 0; r < 4; ++r) t4[r] = (f16)am[r2][r];
            stsv4(lds, MBASE(j), 128, node, (2 * wr + r2) * 16 + lg * 4, t4);
        }
    }
    barrier_lds();
    #pragma unroll 1
    for (int q = tid; q < NT * 32; q += 512) {
        int row = q >> 5;
        int col = (q & 31) * 4;
        f16x4 v0 = ldsv4(lds, VBASE(0), 128, row, col);
        f16x4 v1 = ldsv4(lds, VBASE(1), 128, row, col);
        f16x4 v2 = ldsv4(lds, VBASE(2), 128, row, col);
        f16x4 m0 = ldsv4(lds, MBASE(0), 128, row, col);
        f16x4 m1 = ldsv4(lds, MBASE(1), 128, row, col);
        f16x4 m2 = ldsv4(lds, MBASE(2), 128, row, col);
        f16x4 c0, c1, c2;
        #pragma unroll
        for (int r = 0; r < 4; ++r) {
            c0[r] = (f16)(C111 * ((float)v1[r] * (float)m2[r] - (float)v2[r] * (float)m1[r]));
            c1[r] = (f16)(C111 * ((float)v2[r] * (float)m0[r] - (float)v0[r] * (float)m2[r]));
            c2[r] = (f16)(C111 * ((float)v0[r] * (float)m1[r] - (float)v1[r] * (float)m0[r]));
        }
        stsv4(lds, P5BASE(0), 128, row, col, c0);
        stsv4(lds, P5BASE(1), 128, row, col, c1);
        stsv4(lds, P5BASE(2), 128, row, col, c2);
    }
    // hoist P7's first W1e fragments above the barrier
    f16x8 p7a0 = wfrag(W1ep, 8, 0, 2 * wr, lane);
    f16x8 p7a1 = wfrag(W1ep, 8, 0, 2 * wr + 1, lane);
    barrier_lds();

    // ---- P7: out_1e^T = W1e^T @ p5^T / sqrt(128) (split) ----
    {
        f32x4 acc[2][3] = {};  // [r2][j]
        #pragma unroll
        for (int j = 0; j < 3; ++j)
            #pragma unroll
            for (int ks = 0; ks < 4; ++ks) {
                f16x8 a0 = (j == 0 && ks == 0) ? p7a0 : wfrag(W1ep, 8, ks, 2 * wr, lane);
                f16x8 a1 = (j == 0 && ks == 0) ? p7a1 : wfrag(W1ep, 8, ks, 2 * wr + 1, lane);
                f16x8 b = afrag(lds, P5BASE(j), 128, ng * 16, ks * 32, lr, lg);
                acc[0][j] = MFMA16(a0, b, acc[0][j]);
                acc[1][j] = MFMA16(a1, b, acc[1][j]);
            }
        #pragma unroll
        for (int r2 = 0; r2 < 2; ++r2) {
            int node = ng * 16 + lr;
            if (node < nvalid) {
                int o0 = (2 * wr + r2) * 16 + lg * 4;
                float vals[12];
                #pragma unroll
                for (int r = 0; r < 4; ++r)
                    #pragma unroll
                    for (int j = 0; j < 3; ++j)
                        vals[r * 3 + j] = RS128 * acc[r2][j][r];
                size_t base = (size_t)(z0 + node) * 1024 + 640 + 3 * o0;
                #pragma unroll
                for (int qq = 0; qq < 3; ++qq) {
                    float4 f;
                    f.x = vals[qq * 4 + 0]; f.y = vals[qq * 4 + 1];
                    f.z = vals[qq * 4 + 2]; f.w = vals[qq * 4 + 3];
                    *(float4*)(&out[base + qq * 4]) = f;
                }
            }
        }
    }
}

extern "C" void kernel_launch(void* const* d_in, const int* in_sizes, int n_in,
                              void* d_out, int out_size, void* d_ws, size_t ws_size,
                              hipStream_t stream) {
    const float* nf   = (const float*)d_in[0];
    const float* w00  = (const float*)d_in[1];
    const float* w01  = (const float*)d_in[2];
    const float* w10  = (const float*)d_in[3];
    const float* w110 = (const float*)d_in[4];
    const float* w111 = (const float*)d_in[5];
    const float* W0e  = (const float*)d_in[6];
    const float* W1o  = (const float*)d_in[7];
    const float* W1e  = (const float*)d_in[8];
    f16* wpack = (f16*)d_ws;  // needs 655,360 bytes

    int n_nodes = in_sizes[0] / 640;
    pack_weights<<<1280, 256, 0, stream>>>(w00, w01, w10, w110, w111, W0e, W1o, W1e, wpack);
    int blocks = (n_nodes + NT - 1) / NT;
    node_tp<<<blocks, 512, 0, stream>>>(nf, wpack, (float*)d_out, n_nodes);
}